// Round 6
// baseline (370.017 us; speedup 1.0000x reference)
//
#include <hip/hip_runtime.h>

// ---------------------------------------------------------------------------
// Multiheaded_GRUMix_Attention on MI355X (gfx950). Inputs f32, output f32.
//
// R15:
//  - A operands pre-converted to bf16 in prep (Qbf+Qlo, Kbf, Vbf); gemm128
//    loads A-fragments DIRECTLY into VGPRs (lane-private 16B chunks, double
//    reg-set, loaded 1 step ahead) -> no A LDS, no cvt/ds_write in hot loop.
//  - B-only LDS double-buffer: 32 KB -> __launch_bounds__(256,3), 3 blk/CU.
//  - att stored plain (pre-swizzle no longer needed: A path skips LDS).
//  - gru reverted to R12 LDS-staged version (R13 frag-contiguous variant
//    coincided with ~10us regression).
// attn (R14: MFMA row-sums + exp2-direct + setprio) unchanged.
// ---------------------------------------------------------------------------

typedef __bf16 bf16;
typedef __bf16 bfx8 __attribute__((ext_vector_type(8)));
typedef float v4f __attribute__((ext_vector_type(4)));

__device__ inline float sigm(float x) { return 1.0f / (1.0f + __expf(-x)); }
__device__ inline float tanh_fast(float x) { return 1.0f - 2.0f / (__expf(2.0f * x) + 1.0f); }

__device__ inline v4f mfma16(bfx8 a, bfx8 b, v4f c) {
    return __builtin_amdgcn_mfma_f32_16x16x32_bf16(a, b, c, 0, 0, 0);
}

typedef const __attribute__((address_space(1))) void* gvp;
typedef __attribute__((address_space(3))) void* lvp;

__device__ inline void gload_lds16(const bf16* g, bf16* l) {
    __builtin_amdgcn_global_load_lds((gvp)g, (lvp)l, 16, 0, 0);
}

__device__ inline void split8(const float* __restrict__ p, bfx8& hi, bfx8& lo) {
    float4 x = *(const float4*)p;
    float4 y = *(const float4*)(p + 4);
    float v[8] = {x.x, x.y, x.z, x.w, y.x, y.y, y.z, y.w};
#pragma unroll
    for (int j = 0; j < 8; ++j) {
        bf16 h = (bf16)v[j];
        hi[j] = h;
        lo[j] = (bf16)(v[j] - (float)h);
    }
}

// ---------------------------------------------------------------------------
// prep_kernel roles:
//  [0,320)      trans_w (pre-swizzled bf16 W^T, + lo plane for Wpos)
//  [320,322)    gru weights -> [192][64] hi/lo (R12 layout)
//  [322,834)    mix gate + lengths + mpack
//  [834,3906)   Q/K/V f32 -> bf16 (+ Qlo) streaming convert
// ---------------------------------------------------------------------------
struct PrepArgs {
    const float* wsrc[5]; bf16* wdst[5]; bf16* wdstlo[5];
    const float* gwi; const float* gwh;
    bf16* wih; bf16* wil; bf16* whh; bf16* whl;
    const float* Q; const int* mask; const float* mix_w; const float* mix_b;
    float* mixv; float* stepv; float* lenv; unsigned* mpack;
    const float* Kf; const float* Vf;
    bf16* Qbf; bf16* Qlo; bf16* Kbf; bf16* Vbf;
};

__global__ __launch_bounds__(256) void prep_kernel(PrepArgs a) {
    __shared__ __align__(16) char smraw[17408];
    const int b = blockIdx.x;
    const int t = threadIdx.x;

    if (b < 320) {
        float (*tile)[68] = (float(*)[68])smraw;
        const int wy = b >> 6, bx = b & 63;
        const float* src = a.wsrc[wy];
        bf16* dst = a.wdst[wy];
        bf16* dlo = a.wdstlo[wy];
        const int rbase = (bx >> 3) * 64, cbase = (bx & 7) * 64;
        const int r = t >> 2, cc = (t & 3) * 16;
        {
            const float* p = src + (long)(rbase + r) * 512 + cbase + cc;
            *(float4*)(&tile[r][cc]) = *(const float4*)p;
            *(float4*)(&tile[r][cc + 4]) = *(const float4*)(p + 4);
            *(float4*)(&tile[r][cc + 8]) = *(const float4*)(p + 8);
            *(float4*)(&tile[r][cc + 12]) = *(const float4*)(p + 12);
        }
        __syncthreads();
        bfx8 h0, h1, l0, l1;
#pragma unroll
        for (int j = 0; j < 8; ++j) {
            float v0 = tile[cc + j][r];
            float v1 = tile[cc + 8 + j][r];
            bf16 a0 = (bf16)v0, a1 = (bf16)v1;
            h0[j] = a0; l0[j] = (bf16)(v0 - (float)a0);
            h1[j] = a1; l1[j] = (bf16)(v1 - (float)a1);
        }
        const int n_ = cbase + r;
        const int x_ = (n_ & 7) << 3;
        const long rowo = (long)n_ * 512;
        const int ka = (rbase + cc) ^ x_;
        const int kb = (rbase + cc + 8) ^ x_;
        *(bfx8*)(dst + rowo + ka) = h0;
        *(bfx8*)(dst + rowo + kb) = h1;
        if (dlo) {
            *(bfx8*)(dlo + rowo + ka) = l0;
            *(bfx8*)(dlo + rowo + kb) = l1;
        }
        return;
    }

    if (b < 322) {
        // gru weights -> [192][64] (n-major) hi/lo
        const int m = b - 320;
        const float* src = m ? a.gwh : a.gwi;
        bf16* dh = m ? a.whh : a.wih;
        bf16* dl = m ? a.whl : a.wil;
        for (int e = t; e < 12288; e += 256) {
            int n_ = e >> 6, k = e & 63;
            float v = src[k * 192 + n_];
            bf16 h = (bf16)v;
            dh[e] = h;
            dl[e] = (bf16)(v - (float)h);
        }
        return;
    }

    if (b < 834) {
        unsigned (*mwords)[16] = (unsigned(*)[16])smraw;
        const int bm = b - 322;
        const int qt = bm & 31, n = bm >> 5;
        const int wave = t >> 6, lane = t & 63;
#pragma unroll
        for (int rr = 0; rr < 4; ++rr) {
            const int rloc = wave * 4 + rr;
            const long row = (long)n * 512 + qt * 16 + rloc;
            float dot = 0.f, ms = 0.f;
            unsigned myw = 0;
#pragma unroll
            for (int j = 0; j < 8; ++j) {
                float qv = a.Q[row * 512 + j * 64 + lane];
                float wv = a.mix_w[j * 64 + lane];
                dot += qv * wv;
                int mv = a.mask[row * 512 + j * 64 + lane];
                unsigned long long bl = __ballot(mv != 0);
                ms += (float)__popcll(bl);
                if ((lane >> 1) == j) myw = (unsigned)(bl >> ((lane & 1) * 32));
            }
#pragma unroll
            for (int o = 32; o > 0; o >>= 1) dot += __shfl_xor(dot, o);
            if (lane < 16) mwords[rloc][lane] = myw;
            if (lane == 0) {
                a.mixv[row] = sigm(dot + a.mix_b[0]);
                a.lenv[row] = ms;
                a.stepv[row] = 1.0f / fmaxf(1.0f, ms - 1.0f);
            }
        }
        __syncthreads();
        {
            const int quad = (lane >> 4), c = lane & 15;
            unsigned out = 0;
#pragma unroll
            for (int i = 0; i < 4; ++i) {
                const int rl = quad * 4 + i;
                unsigned w0 = mwords[rl][wave * 4 + 0];
                unsigned w1 = mwords[rl][wave * 4 + 1];
                unsigned w2 = mwords[rl][wave * 4 + 2];
                unsigned w3 = mwords[rl][wave * 4 + 3];
                unsigned byte_ = ((w0 >> c) & 1u) | (((w0 >> (16 + c)) & 1u) << 1) |
                                 (((w1 >> c) & 1u) << 2) | (((w1 >> (16 + c)) & 1u) << 3) |
                                 (((w2 >> c) & 1u) << 4) | (((w2 >> (16 + c)) & 1u) << 5) |
                                 (((w3 >> c) & 1u) << 6) | (((w3 >> (16 + c)) & 1u) << 7);
                out |= byte_ << (8 * i);
            }
            a.mpack[(long)bm * 256 + t] = out;
        }
        return;
    }

    // ---- f32 -> bf16 conversion (Q: hi+lo, K, V: hi)
    const int cb = b - 834;
    const int tensor = cb >> 10;
    const long off = ((long)(cb & 1023) * 256 + t) * 16;
    const float* s_ = tensor == 0 ? a.Q : (tensor == 1 ? a.Kf : a.Vf);
    const float4* sp = (const float4*)(s_ + off);
    float4 x0 = sp[0], x1 = sp[1], x2 = sp[2], x3 = sp[3];
    float v[16] = {x0.x, x0.y, x0.z, x0.w, x1.x, x1.y, x1.z, x1.w,
                   x2.x, x2.y, x2.z, x2.w, x3.x, x3.y, x3.z, x3.w};
    bfx8 h0, h1, l0, l1;
#pragma unroll
    for (int j = 0; j < 8; ++j) {
        bf16 ha = (bf16)v[j], hb = (bf16)v[8 + j];
        h0[j] = ha; h1[j] = hb;
        l0[j] = (bf16)(v[j] - (float)ha);
        l1[j] = (bf16)(v[8 + j] - (float)hb);
    }
    bf16* dh = tensor == 0 ? a.Qbf : (tensor == 1 ? a.Kbf : a.Vbf);
    *(bfx8*)(dh + off) = h0;
    *(bfx8*)(dh + off + 8) = h1;
    if (tensor == 0) {
        *(bfx8*)(a.Qlo + off) = l0;
        *(bfx8*)(a.Qlo + off + 8) = l1;
    }
}

// ---------------------------------------------------------------------------
// Unified 128x128 GEMM: A in registers (bf16, double set, 1-step prefetch),
// B via global_load_lds double-buffer (32 KB LDS). modes:
//  0: C bf16 [M][512] (*cscale)   1: C^T bf16 (VhT)
//  2: split hi/lo + relu+bias (K'=1536: AhBh, AhBl, AlBh)
//  3: C f32 [M][512]
// ---------------------------------------------------------------------------
struct GEMMDesc {
    const bf16* A0;
    const bf16* A1;
    const bf16* B0;
    const bf16* B1;
    const float* bias;
    bf16* Cb;
    bf16* Cl;
    float* Cf;
    int mode;
    float cscale;
};
struct G4 { GEMMDesc d[4]; };

__global__ __launch_bounds__(256, 3) void gemm128(G4 gg) {
    __shared__ bf16 sm[16384];   // 2 x Bs[128][64]
    bf16* Bs0 = sm;
    bf16* Bs1 = sm + 8192;

    const GEMMDesc g = gg.d[blockIdx.z];
    const int mode = g.mode;
    const int mbase = blockIdx.x * 128, nbase = blockIdx.y * 128;
    const int t = threadIdx.x, w = t >> 6, l = t & 63;
    const int quad = l >> 4, c = l & 15;
    const int wr = w >> 1, wc = w & 1;

    const v4f zero4 = {0.f, 0.f, 0.f, 0.f};
    v4f acc[4][4];
#pragma unroll
    for (int m = 0; m < 4; ++m)
#pragma unroll
        for (int nn = 0; nn < 4; ++nn) acc[m][nn] = zero4;

    const int nsteps = (mode == 2) ? 24 : 8;
    const int xm = c & 7;
    const int slot0 = w * 4;
    const int srow = l >> 3;
    const int sch8 = (l & 7) * 8;
    // per-lane A row base (lane-private fragment rows)
    const long arow = (long)(mbase + wr * 64 + c) * 512 + quad * 8;

    auto issueB = [&](int s, bf16* Bs) {
        const bf16* Bsrc = (mode == 2 && ((s >> 3) == 1)) ? g.B1 : g.B0;
        const int k0 = (mode == 2) ? (s & 7) * 64 : s * 64;
#pragma unroll
        for (int j = 0; j < 4; ++j) {
            int sl = slot0 + j;
            int row = sl * 8 + srow;
            gload_lds16(Bsrc + (long)(nbase + row) * 512 + k0 + sch8, Bs + sl * 512);
        }
    };

    auto loadA = [&](int s, bfx8 (&dst)[8]) {
        const bf16* Asrc = (mode == 2 && ((s >> 3) == 2)) ? g.A1 : g.A0;
        const int k0 = (mode == 2) ? (s & 7) * 64 : s * 64;
#pragma unroll
        for (int m = 0; m < 4; ++m) {
            const bf16* pr = Asrc + arow + (long)m * 16 * 512 + k0;
            dst[m * 2 + 0] = *(const bfx8*)pr;
            dst[m * 2 + 1] = *(const bfx8*)(pr + 32);
        }
    };

    auto computeB = [&](const bf16* Bs, const bfx8 (&af)[8]) {
#pragma unroll
        for (int ks = 0; ks < 2; ++ks) {
            const int off = (((ks * 4 + quad) ^ xm) * 8);
            bfx8 bb[4];
#pragma unroll
            for (int nn = 0; nn < 4; ++nn)
                bb[nn] = *(const bfx8*)(&Bs[(wc * 64 + nn * 16 + c) * 64 + off]);
#pragma unroll
            for (int m = 0; m < 4; ++m)
#pragma unroll
                for (int nn = 0; nn < 4; ++nn)
                    acc[m][nn] = mfma16(af[m * 2 + ks], bb[nn], acc[m][nn]);
        }
    };

    bfx8 aA[8], aB[8];
    issueB(0, Bs0);
    loadA(0, aA);
    __syncthreads();
    for (int s = 0; s < nsteps; s += 2) {
        issueB(s + 1, Bs1);
        loadA(s + 1, aB);
        computeB(Bs0, aA);
        __syncthreads();
        const bool more = (s + 2 < nsteps);
        if (more) {
            issueB(s + 2, Bs0);
            loadA(s + 2, aA);
        }
        computeB(Bs1, aB);
        __syncthreads();
    }

    // ---- epilogues
    if (mode == 3) {
        float* C = g.Cf;
#pragma unroll
        for (int m = 0; m < 4; ++m)
#pragma unroll
            for (int nn = 0; nn < 4; ++nn)
#pragma unroll
                for (int i = 0; i < 4; ++i) {
                    int row = mbase + wr * 64 + m * 16 + quad * 4 + i;
                    int col = nbase + wc * 64 + nn * 16 + c;
                    C[(long)row * 512 + col] = acc[m][nn][i];
                }
        return;
    }

    if (mode == 1) {
        bf16* CT = g.Cb + ((long)(mbase >> 9)) * 262144;
        const int s0 = mbase & 511;
        for (int h = 0; h < 2; ++h) {
            if (wr == h) {
#pragma unroll
                for (int m = 0; m < 4; ++m)
#pragma unroll
                    for (int nn = 0; nn < 4; ++nn)
#pragma unroll
                        for (int i = 0; i < 4; ++i)
                            sm[(wc * 64 + nn * 16 + c) * 64 + m * 16 + quad * 4 + i] =
                                (bf16)acc[m][nn][i];
            }
            __syncthreads();
            {
                const bf16* src = sm + (t >> 1) * 64 + (t & 1) * 32;
                bf16* d = CT + (long)(nbase + (t >> 1)) * 512 + s0 + h * 64 + (t & 1) * 32;
#pragma unroll
                for (int j = 0; j < 4; ++j) *(bfx8*)(d + j * 8) = *(const bfx8*)(src + j * 8);
            }
            __syncthreads();
        }
        return;
    }

    // modes 0 / 2: row-major bf16 via LDS pack
    for (int h = 0; h < 2; ++h) {
        if (wr == h) {
#pragma unroll
            for (int m = 0; m < 4; ++m)
#pragma unroll
                for (int nn = 0; nn < 4; ++nn)
#pragma unroll
                    for (int i = 0; i < 4; ++i) {
                        int col = wc * 64 + nn * 16 + c;
                        float v = acc[m][nn][i];
                        if (mode == 2) v = fmaxf(v + g.bias[nbase + col], 0.f);
                        else v *= g.cscale;
                        bf16 hv = (bf16)v;
                        sm[(m * 16 + quad * 4 + i) * 128 + col] = hv;
                        if (mode == 2)
                            sm[8192 + (m * 16 + quad * 4 + i) * 128 + col] =
                                (bf16)(v - (float)hv);
                    }
        }
        __syncthreads();
        {
            const int row = t >> 2, seg = t & 3;
            const bf16* src = sm + row * 128 + seg * 32;
            bf16* d = g.Cb + (long)(mbase + h * 64 + row) * 512 + nbase + seg * 32;
#pragma unroll
            for (int j = 0; j < 4; ++j) *(bfx8*)(d + j * 8) = *(const bfx8*)(src + j * 8);
            if (mode == 2) {
                const bf16* src2 = sm + 8192 + row * 128 + seg * 32;
                bf16* d2 = g.Cl + (long)(mbase + h * 64 + row) * 512 + nbase + seg * 32;
#pragma unroll
                for (int j = 0; j < 4; ++j) *(bfx8*)(d2 + j * 8) = *(const bfx8*)(src2 + j * 8);
            }
        }
        __syncthreads();
    }
}

// ---------------------------------------------------------------------------
// Fused GRU (R12 version): LDS-staged weights, split Xg + split hp, fast tanh.
// ---------------------------------------------------------------------------
__global__ __launch_bounds__(256) void gru_fused_kernel(
    const bf16* __restrict__ Xh, const bf16* __restrict__ Xl,
    const float* __restrict__ hp,
    const bf16* __restrict__ wih, const bf16* __restrict__ wil,
    const bf16* __restrict__ whh, const bf16* __restrict__ whl,
    const float* __restrict__ gbi, const float* __restrict__ gbh,
    const float* __restrict__ pa, const float* __restrict__ Wsigma,
    const float* __restrict__ Wrho,
    const float* __restrict__ lenv, const float* __restrict__ stepv,
    float* __restrict__ muv, float* __restrict__ sigv) {
    __shared__ bf16 Wh[192][72], Wl[192][72];
    __shared__ float biL[384];

    const int b = blockIdx.x;
    const int qb = b & 7, nh = b >> 3, hd = nh & 7, n = nh >> 3;
    const int t = threadIdx.x;
    const int w = t >> 6, lane = t & 63, quad = lane >> 4, c = lane & 15;
    const int q0 = qb * 64 + w * 16;

    if (t < 192) { biL[t] = gbi[t]; biL[192 + t] = gbh[t]; }
#pragma unroll
    for (int it = 0; it < 6; ++it) {
        int task = it * 256 + t;
        int r = task >> 3, ch = task & 7;
        *(bfx8*)(&Wh[r][ch * 8]) = *(const bfx8*)(wih + r * 64 + ch * 8);
        *(bfx8*)(&Wl[r][ch * 8]) = *(const bfx8*)(wil + r * 64 + ch * 8);
    }
    __syncthreads();

    const v4f zero4 = {0.f, 0.f, 0.f, 0.f};
    v4f gi[12], gh[12];
#pragma unroll
    for (int nt = 0; nt < 12; ++nt) gi[nt] = zero4;
#pragma unroll
    for (int ks = 0; ks < 2; ++ks) {
        long ao = (long)(n * 512 + q0 + c) * 512 + hd * 64 + ks * 32 + quad * 8;
        bfx8 xh = *(const bfx8*)(Xh + ao);
        bfx8 xl = *(const bfx8*)(Xl + ao);
#pragma unroll
        for (int nt = 0; nt < 12; ++nt) {
            bfx8 bh = *(const bfx8*)(&Wh[nt * 16 + c][ks * 32 + quad * 8]);
            bfx8 bl = *(const bfx8*)(&Wl[nt * 16 + c][ks * 32 + quad * 8]);
            gi[nt] = mfma16(xh, bh, gi[nt]);
            gi[nt] = mfma16(xh, bl, gi[nt]);
            gi[nt] = mfma16(xl, bh, gi[nt]);
        }
    }
    __syncthreads();
#pragma unroll
    for (int it = 0; it < 6; ++it) {
        int task = it * 256 + t;
        int r = task >> 3, ch = task & 7;
        *(bfx8*)(&Wh[r][ch * 8]) = *(const bfx8*)(whh + r * 64 + ch * 8);
        *(bfx8*)(&Wl[r][ch * 8]) = *(const bfx8*)(whl + r * 64 + ch * 8);
    }
    __syncthreads();
#pragma unroll
    for (int nt = 0; nt < 12; ++nt) gh[nt] = zero4;
#pragma unroll
    for (int ks = 0; ks < 2; ++ks) {
        bfx8 ah, al;
        split8(hp + (long)(nh * 512 + q0 + c) * 64 + ks * 32 + quad * 8, ah, al);
#pragma unroll
        for (int nt = 0; nt < 12; ++nt) {
            bfx8 bh = *(const bfx8*)(&Wh[nt * 16 + c][ks * 32 + quad * 8]);
            bfx8 bl = *(const bfx8*)(&Wl[nt * 16 + c][ks * 32 + quad * 8]);
            gh[nt] = mfma16(ah, bh, gh[nt]);
            gh[nt] = mfma16(ah, bl, gh[nt]);
            gh[nt] = mfma16(al, bh, gh[nt]);
        }
    }

    float st[4][4];
#pragma unroll
    for (int t4 = 0; t4 < 4; ++t4) {
        float bir = biL[t4 * 16 + c];
        float biz = biL[64 + t4 * 16 + c];
        float bin = biL[128 + t4 * 16 + c];
        float bhr = biL[192 + t4 * 16 + c];
        float bhz = biL[256 + t4 * 16 + c];
        float bhn = biL[320 + t4 * 16 + c];
#pragma unroll
        for (int i = 0; i < 4; ++i) {
            int row = q0 + quad * 4 + i;
            float r = sigm(gi[t4][i] + bir + gh[t4][i] + bhr);
            float z = sigm(gi[t4 + 4][i] + biz + gh[t4 + 4][i] + bhz);
            float nn_ = tanh_fast(gi[t4 + 8][i] + bin + r * (gh[t4 + 8][i] + bhn));
            float hpv = hp[(long)(nh * 512 + row) * 64 + t4 * 16 + c];
            st[t4][i] = (1.0f - z) * nn_ + z * hpv;
        }
    }

    float ws_[4], wr0[4], wr1[4], wr2[4];
#pragma unroll
    for (int t4 = 0; t4 < 4; ++t4) {
        int d = t4 * 16 + c;
        ws_[t4] = Wsigma[hd * 64 + d];
        wr0[t4] = Wrho[(hd * 64 + d) * 3 + 0];
        wr1[t4] = Wrho[(hd * 64 + d) * 3 + 1];
        wr2[t4] = Wrho[(hd * 64 + d) * 3 + 2];
    }
#pragma unroll
    for (int i = 0; i < 4; ++i) {
        float s0 = 0.f, s1 = 0.f, s2 = 0.f, s3 = 0.f;
#pragma unroll
        for (int t4 = 0; t4 < 4; ++t4) {
            float sv = st[t4][i];
            s0 += sv * ws_[t4];
            s1 += sv * wr0[t4];
            s2 += sv * wr1[t4];
            s3 += sv * wr2[t4];
        }
#pragma unroll
        for (int o = 1; o < 16; o <<= 1) {
            s0 += __shfl_xor(s0, o);
            s1 += __shfl_xor(s1, o);
            s2 += __shfl_xor(s2, o);
            s3 += __shfl_xor(s3, o);
        }
        if (c == 0) {
            int row = q0 + quad * 4 + i;
            int idx = nh * 512 + row, rq = n * 512 + row;
            float L = lenv[rq], sp = stepv[rq];
            float sg = (fmaxf(s0, 0.f) + 0.27f) / L;
            float fl = floorf(s1);
            float steps = fl + sigm(10.0f * (fabsf(s1 - fl) - 0.5f));
            float ag = sigm(s2), bg = sigm(s3);
            float mu_ = steps * sp + ag * pa[idx] + bg;
            float mu = fmaxf(0.01f * mu_, fminf(mu_, 1.0f + 0.01f * mu_));
            muv[idx] = mu;
            sigv[idx] = sg;
        }
    }
}

// ---------------------------------------------------------------------------
// Fused attention (R14): single barrier; MFMA row-sums; exp2-direct.
// att stored PLAIN (gemm128 A path no longer uses LDS swizzle).
// ---------------------------------------------------------------------------
__global__ __launch_bounds__(256) void attn_fused_kernel(
    const bf16* __restrict__ Qh, const bf16* __restrict__ Kh,
    const bf16* __restrict__ VhT, const unsigned* __restrict__ mpack,
    const float* __restrict__ vpos, const float* __restrict__ mixv,
    const float* __restrict__ stepv, const float* __restrict__ muv,
    const float* __restrict__ sigv, bf16* __restrict__ att) {
    __shared__ bf16 Pp[16][520];
    __shared__ bf16 Pg[16][520];

    const int b = blockIdx.x;
    const int nh = ((b >> 8) << 3) | (b & 7);
    const int qt = (b >> 3) & 31;
    const int hd = nh & 7, n = nh >> 3;
    const int t = threadIdx.x;
    const int wave = t >> 6, lane = t & 63;
    const int quad = lane >> 4, c = lane & 15;
    const int qloc = quad * 4;

    const bf16* qrow = Qh + (long)(n * 512 + qt * 16 + c) * 512 + hd * 64 + quad * 8;
    bfx8 afr0 = *(const bfx8*)qrow;
    bfx8 afr1 = *(const bfx8*)(qrow + 32);

    const v4f zero4 = {0.f, 0.f, 0.f, 0.f};
    v4f acc[8];
#pragma unroll
    for (int i = 0; i < 8; ++i) acc[i] = zero4;

    const bf16* kbase = Kh + (long)(n * 512 + wave * 128 + c) * 512 + hd * 64 + quad * 8;
#pragma unroll
    for (int t8 = 0; t8 < 8; ++t8) {
        bfx8 b0 = *(const bfx8*)(kbase + (long)t8 * 16 * 512);
        bfx8 b1 = *(const bfx8*)(kbase + (long)t8 * 16 * 512 + 32);
        acc[t8] = mfma16(afr0, b0, acc[t8]);
        acc[t8] = mfma16(afr1, b1, acc[t8]);
    }

    float mu_[4], c2n[4], stp[4];
#pragma unroll
    for (int i = 0; i < 4; ++i) {
        int q = qt * 16 + qloc + i;
        int idx = nh * 512 + q, rq = n * 512 + q;
        mu_[i] = muv[idx];
        float sg = sigv[idx];
        c2n[i] = -0.72134752f / (sg * sg);   // -0.5*log2(e)/sigma^2
        stp[i] = stepv[rq];
    }

    const unsigned mb32 = mpack[(long)(n * 32 + qt) * 256 + t];
    unsigned mbits[4];
#pragma unroll
    for (int i = 0; i < 4; ++i) mbits[i] = (mb32 >> (8 * i)) & 0xffu;

    float vp[8];
#pragma unroll
    for (int t8 = 0; t8 < 8; ++t8) vp[t8] = vpos[wave * 128 + t8 * 16 + c];

#pragma unroll
    for (int i = 0; i < 4; ++i) {
        float m = mu_[i], s = stp[i], cg = c2n[i];
#pragma unroll
        for (int t8 = 0; t8 < 8; ++t8) {
            int on = (mbits[i] >> t8) & 1;
            float pv = on ? __builtin_amdgcn_exp2f(acc[t8][i]) : 0.f;
            float d = vp[t8] * s - m;
            float gv = on ? __builtin_amdgcn_exp2f(d * d * cg) : 0.f;
            int k = wave * 128 + t8 * 16 + c;
            Pp[qloc + i][k] = (bf16)pv;
            Pg[qloc + i][k] = (bf16)gv;
        }
    }

    __syncthreads();  // the ONLY barrier

    bfx8 ones;
#pragma unroll
    for (int j = 0; j < 8; ++j) ones[j] = (bf16)1.0f;

    v4f accP = zero4, accG = zero4, accS = zero4, accT = zero4;
    const bf16* vrow = VhT + (long)(n * 512 + hd * 64 + wave * 16 + c) * 512 + quad * 8;
    __builtin_amdgcn_s_setprio(1);
#pragma unroll
    for (int ks = 0; ks < 16; ++ks) {
        bfx8 bf_ = *(const bfx8*)(vrow + ks * 32);
        bfx8 ap = *(const bfx8*)(&Pp[c][ks * 32 + quad * 8]);
        bfx8 ag = *(const bfx8*)(&Pg[c][ks * 32 + quad * 8]);
        accP = mfma16(ap, bf_, accP);
        accG = mfma16(ag, bf_, accG);
        accS = mfma16(ap, ones, accS);
        accT = mfma16(ag, ones, accT);
    }
    __builtin_amdgcn_s_setprio(0);

#pragma unroll
    for (int i = 0; i < 4; ++i) {
        float Sp = accS[i];
        float Sg = accT[i] + 512.0f * 1e-20f;
        float m_ = mixv[n * 512 + qt * 16 + qloc + i];
        float aci = (1.0f - m_) / Sp;
        float bci = m_ / Sg;
        int q = qt * 16 + quad * 4 + i;
        att[(long)(n * 512 + q) * 512 + hd * 64 + wave * 16 + c] =
            (bf16)(aci * accP[i] + bci * accG[i]);
    }
}

// ---------------------------------------------------------------------------
extern "C" void kernel_launch(void* const* d_in, const int* in_sizes, int n_in,
                              void* d_out, int out_size, void* d_ws, size_t ws_size,
                              hipStream_t stream) {
    (void)in_sizes; (void)n_in; (void)out_size; (void)ws_size;

    const float* Q = (const float*)d_in[0];
    const float* K = (const float*)d_in[1];
    const float* V = (const float*)d_in[2];
    const float* past_state = (const float*)d_in[3];
    const float* past_att = (const float*)d_in[4];
    const float* vpos = (const float*)d_in[5];
    const int* mask = (const int*)d_in[6];
    const float* Wq = (const float*)d_in[7];
    const float* Wk = (const float*)d_in[8];
    const float* Wv = (const float*)d_in[9];
    const float* Wpos = (const float*)d_in[10];
    const float* bpos = (const float*)d_in[11];
    const float* Wsigma = (const float*)d_in[12];
    const float* Wrho = (const float*)d_in[13];
    const float* mix_w = (const float*)d_in[14];
    const float* mix_b = (const float*)d_in[15];
    const float* gwi = (const float*)d_in[16];
    const float* gwh = (const float*)d_in[17];
    const float* gbi = (const float*)d_in[18];
    const float* gbh = (const float*)d_in[19];
    const float* Wc = (const float*)d_in[20];
    float* out = (float*)d_out;

    // ---- workspace ----
    char* p = (char*)d_ws;
    const size_t SZB = 8192UL * 512 * 2;
    const size_t SZW = 512UL * 512 * 2;
    bf16* WqT = (bf16*)p;   p += SZW;
    bf16* WkT = (bf16*)p;   p += SZW;
    bf16* WvT = (bf16*)p;   p += SZW;
    bf16* WpT = (bf16*)p;   p += SZW;
    bf16* WpTl = (bf16*)p;  p += SZW;
    bf16* WcT = (bf16*)p;   p += SZW;
    bf16* wih = (bf16*)p;   p += 24576;
    bf16* wil = (bf16*)p;   p += 24576;
    bf16* whh = (bf16*)p;   p += 24576;
    bf16* whl = (bf16*)p;   p += 24576;
    bf16* Qh = (bf16*)p;    p += SZB;
    bf16* Kh = (bf16*)p;    p += SZB;
    bf16* VhT = (bf16*)p;   p += SZB;
    bf16* Xh = (bf16*)p;
    bf16* att = Xh;         p += SZB;
    bf16* Xl = (bf16*)p;    p += SZB;
    bf16* Qbf = (bf16*)p;   p += SZB;
    bf16* Qlo = (bf16*)p;   p += SZB;
    bf16* Kbf = (bf16*)p;   p += SZB;
    bf16* Vbf = (bf16*)p;   p += SZB;
    unsigned* mpack = (unsigned*)p;      p += 16UL * 32 * 256 * 4;
    float* mixv = (float*)p;  p += 32768;
    float* stepv = (float*)p; p += 32768;
    float* lenv = (float*)p;  p += 32768;
    float* muv = (float*)p;   p += 262144;
    float* sigv = (float*)p;  p += 262144;

    dim3 blk(256);

    PrepArgs pa;
    pa.wsrc[0] = Wq; pa.wsrc[1] = Wk; pa.wsrc[2] = Wv; pa.wsrc[3] = Wpos; pa.wsrc[4] = Wc;
    pa.wdst[0] = WqT; pa.wdst[1] = WkT; pa.wdst[2] = WvT; pa.wdst[3] = WpT; pa.wdst[4] = WcT;
    pa.wdstlo[0] = nullptr; pa.wdstlo[1] = nullptr; pa.wdstlo[2] = nullptr;
    pa.wdstlo[3] = WpTl; pa.wdstlo[4] = nullptr;
    pa.gwi = gwi; pa.gwh = gwh;
    pa.wih = wih; pa.wil = wil; pa.whh = whh; pa.whl = whl;
    pa.Q = Q; pa.mask = mask; pa.mix_w = mix_w; pa.mix_b = mix_b;
    pa.mixv = mixv; pa.stepv = stepv; pa.lenv = lenv; pa.mpack = mpack;
    pa.Kf = K; pa.Vf = V;
    pa.Qbf = Qbf; pa.Qlo = Qlo; pa.Kbf = Kbf; pa.Vbf = Vbf;
    prep_kernel<<<dim3(3906), blk, 0, stream>>>(pa);

    // projections: d[0]=split (longest, z=0 first), d[1]=Q (cscale for exp2),
    // d[2]=K, d[3]=V(T)
    G4 gp;
    gp.d[0].A0 = Qbf; gp.d[0].A1 = Qlo; gp.d[0].B0 = WpT; gp.d[0].B1 = WpTl;
    gp.d[0].bias = bpos; gp.d[0].Cb = Xh; gp.d[0].Cl = Xl; gp.d[0].Cf = nullptr;
    gp.d[0].mode = 2; gp.d[0].cscale = 1.0f;
    gp.d[1].A0 = Qbf; gp.d[1].A1 = nullptr; gp.d[1].B0 = WqT; gp.d[1].B1 = nullptr;
    gp.d[1].bias = nullptr; gp.d[1].Cb = Qh; gp.d[1].Cl = nullptr; gp.d[1].Cf = nullptr;
    gp.d[1].mode = 0; gp.d[1].cscale = 0.125f * 1.44269504089f;
    gp.d[2].A0 = Kbf; gp.d[2].A1 = nullptr; gp.d[2].B0 = WkT; gp.d[2].B1 = nullptr;
    gp.d[2].bias = nullptr; gp.d[2].Cb = Kh; gp.d[2].Cl = nullptr; gp.d[2].Cf = nullptr;
    gp.d[2].mode = 0; gp.d[2].cscale = 1.0f;
    gp.d[3].A0 = Vbf; gp.d[3].A1 = nullptr; gp.d[3].B0 = WvT; gp.d[3].B1 = nullptr;
    gp.d[3].bias = nullptr; gp.d[3].Cb = VhT; gp.d[3].Cl = nullptr; gp.d[3].Cf = nullptr;
    gp.d[3].mode = 1; gp.d[3].cscale = 1.0f;
    gemm128<<<dim3(64, 4, 4), blk, 0, stream>>>(gp);

    gru_fused_kernel<<<dim3(1024), blk, 0, stream>>>(
        Xh, Xl, past_state, wih, wil, whh, whl, gbi, gbh, past_att, Wsigma, Wrho,
        lenv, stepv, muv, sigv);

    attn_fused_kernel<<<dim3(4096), blk, 0, stream>>>(
        Qh, Kh, VhT, mpack, vpos, mixv, stepv, muv, sigv, att);

    G4 go;
    go.d[0].A0 = att; go.d[0].A1 = nullptr; go.d[0].B0 = WcT; go.d[0].B1 = nullptr;
    go.d[0].bias = nullptr; go.d[0].Cb = nullptr; go.d[0].Cl = nullptr; go.d[0].Cf = out;
    go.d[0].mode = 3; go.d[0].cscale = 1.0f;
    go.d[1] = go.d[0]; go.d[2] = go.d[0]; go.d[3] = go.d[0];  // unused
    gemm128<<<dim3(64, 4, 1), blk, 0, stream>>>(go);
}

// Round 7
// 340.839 us; speedup vs baseline: 1.0856x; 1.0856x over previous
//
#include <hip/hip_runtime.h>

// ---------------------------------------------------------------------------
// Multiheaded_GRUMix_Attention on MI355X (gfx950). Inputs f32, output f32.
//
// R16: gemm128 = R14 structure (f32-A reg-stage + convert, gload_lds B,
// 2-phase double-buffer) with ONE change: BK 64 -> 32.
//   - LDS 64 -> 32 KB => __launch_bounds__(256,3), 3 blocks/CU (+50% waves;
//     counters said latency-bound at 20% occupancy on every pipe).
//   - swizzle narrows to 32-elem groups: trans_w stores k^((col&3)<<3),
//     attn stores att col^(row&3)<<3, writeA chunk^(row&3); ds_read offset
//     (quad^(c&3))*8 is now loop-invariant.
// R15's A-in-VGPR + Q/K/V preconvert REVERTED (regressed: worse coalescing,
// lost latency-hiding VALU). gru = R12 LDS version; attn = R14 version.
// ---------------------------------------------------------------------------

typedef __bf16 bf16;
typedef __bf16 bfx8 __attribute__((ext_vector_type(8)));
typedef float v4f __attribute__((ext_vector_type(4)));

__device__ inline float sigm(float x) { return 1.0f / (1.0f + __expf(-x)); }
__device__ inline float tanh_fast(float x) { return 1.0f - 2.0f / (__expf(2.0f * x) + 1.0f); }

__device__ inline v4f mfma16(bfx8 a, bfx8 b, v4f c) {
    return __builtin_amdgcn_mfma_f32_16x16x32_bf16(a, b, c, 0, 0, 0);
}

typedef const __attribute__((address_space(1))) void* gvp;
typedef __attribute__((address_space(3))) void* lvp;

__device__ inline void gload_lds16(const bf16* g, bf16* l) {
    __builtin_amdgcn_global_load_lds((gvp)g, (lvp)l, 16, 0, 0);
}

__device__ inline void split8(const float* __restrict__ p, bfx8& hi, bfx8& lo) {
    float4 x = *(const float4*)p;
    float4 y = *(const float4*)(p + 4);
    float v[8] = {x.x, x.y, x.z, x.w, y.x, y.y, y.z, y.w};
#pragma unroll
    for (int j = 0; j < 8; ++j) {
        bf16 h = (bf16)v[j];
        hi[j] = h;
        lo[j] = (bf16)(v[j] - (float)h);
    }
}

// ---------------------------------------------------------------------------
// prep_kernel roles:
//  [0,320)    trans_w: bf16 W^T[col][k'], k' = k ^ ((col&3)<<3)  (BK=32 swz)
//  [320,322)  gru weights -> [192][64] hi/lo
//  [322,834)  mix gate + lengths + mpack
// ---------------------------------------------------------------------------
struct PrepArgs {
    const float* wsrc[5]; bf16* wdst[5]; bf16* wdstlo[5];
    const float* gwi; const float* gwh;
    bf16* wih; bf16* wil; bf16* whh; bf16* whl;
    const float* Q; const int* mask; const float* mix_w; const float* mix_b;
    float* mixv; float* stepv; float* lenv; unsigned* mpack;
};

__global__ __launch_bounds__(256) void prep_kernel(PrepArgs a) {
    __shared__ __align__(16) char smraw[17408];
    const int b = blockIdx.x;
    const int t = threadIdx.x;

    if (b < 320) {
        float (*tile)[68] = (float(*)[68])smraw;
        const int wy = b >> 6, bx = b & 63;
        const float* src = a.wsrc[wy];
        bf16* dst = a.wdst[wy];
        bf16* dlo = a.wdstlo[wy];
        const int rbase = (bx >> 3) * 64, cbase = (bx & 7) * 64;
        const int r = t >> 2, cc = (t & 3) * 16;
        {
            const float* p = src + (long)(rbase + r) * 512 + cbase + cc;
            *(float4*)(&tile[r][cc]) = *(const float4*)p;
            *(float4*)(&tile[r][cc + 4]) = *(const float4*)(p + 4);
            *(float4*)(&tile[r][cc + 8]) = *(const float4*)(p + 8);
            *(float4*)(&tile[r][cc + 12]) = *(const float4*)(p + 12);
        }
        __syncthreads();
        bfx8 h0, h1, l0, l1;
#pragma unroll
        for (int j = 0; j < 8; ++j) {
            float v0 = tile[cc + j][r];
            float v1 = tile[cc + 8 + j][r];
            bf16 a0 = (bf16)v0, a1 = (bf16)v1;
            h0[j] = a0; l0[j] = (bf16)(v0 - (float)a0);
            h1[j] = a1; l1[j] = (bf16)(v1 - (float)a1);
        }
        const int n_ = cbase + r;
        const int x_ = (n_ & 3) << 3;             // BK=32 swizzle: k bits [4:3]
        const long rowo = (long)n_ * 512;
        const int ka = (rbase + cc) ^ x_;
        const int kb = (rbase + cc + 8) ^ x_;
        *(bfx8*)(dst + rowo + ka) = h0;
        *(bfx8*)(dst + rowo + kb) = h1;
        if (dlo) {
            *(bfx8*)(dlo + rowo + ka) = l0;
            *(bfx8*)(dlo + rowo + kb) = l1;
        }
        return;
    }

    if (b < 322) {
        const int m = b - 320;
        const float* src = m ? a.gwh : a.gwi;
        bf16* dh = m ? a.whh : a.wih;
        bf16* dl = m ? a.whl : a.wil;
        for (int e = t; e < 12288; e += 256) {
            int n_ = e >> 6, k = e & 63;
            float v = src[k * 192 + n_];
            bf16 h = (bf16)v;
            dh[e] = h;
            dl[e] = (bf16)(v - (float)h);
        }
        return;
    }

    unsigned (*mwords)[16] = (unsigned(*)[16])smraw;
    const int bm = b - 322;
    const int qt = bm & 31, n = bm >> 5;
    const int wave = t >> 6, lane = t & 63;
#pragma unroll
    for (int rr = 0; rr < 4; ++rr) {
        const int rloc = wave * 4 + rr;
        const long row = (long)n * 512 + qt * 16 + rloc;
        float dot = 0.f, ms = 0.f;
        unsigned myw = 0;
#pragma unroll
        for (int j = 0; j < 8; ++j) {
            float qv = a.Q[row * 512 + j * 64 + lane];
            float wv = a.mix_w[j * 64 + lane];
            dot += qv * wv;
            int mv = a.mask[row * 512 + j * 64 + lane];
            unsigned long long bl = __ballot(mv != 0);
            ms += (float)__popcll(bl);
            if ((lane >> 1) == j) myw = (unsigned)(bl >> ((lane & 1) * 32));
        }
#pragma unroll
        for (int o = 32; o > 0; o >>= 1) dot += __shfl_xor(dot, o);
        if (lane < 16) mwords[rloc][lane] = myw;
        if (lane == 0) {
            a.mixv[row] = sigm(dot + a.mix_b[0]);
            a.lenv[row] = ms;
            a.stepv[row] = 1.0f / fmaxf(1.0f, ms - 1.0f);
        }
    }
    __syncthreads();
    {
        const int quad = (lane >> 4), c = lane & 15;
        unsigned out = 0;
#pragma unroll
        for (int i = 0; i < 4; ++i) {
            const int rl = quad * 4 + i;
            unsigned w0 = mwords[rl][wave * 4 + 0];
            unsigned w1 = mwords[rl][wave * 4 + 1];
            unsigned w2 = mwords[rl][wave * 4 + 2];
            unsigned w3 = mwords[rl][wave * 4 + 3];
            unsigned byte_ = ((w0 >> c) & 1u) | (((w0 >> (16 + c)) & 1u) << 1) |
                             (((w1 >> c) & 1u) << 2) | (((w1 >> (16 + c)) & 1u) << 3) |
                             (((w2 >> c) & 1u) << 4) | (((w2 >> (16 + c)) & 1u) << 5) |
                             (((w3 >> c) & 1u) << 6) | (((w3 >> (16 + c)) & 1u) << 7);
            out |= byte_ << (8 * i);
        }
        a.mpack[(long)bm * 256 + t] = out;
    }
}

// ---------------------------------------------------------------------------
// Unified 128x128 GEMM, BK=32, 2-phase double-buffered, 3 blocks/CU.
//  modes: 0 C bf16 (*cscale); 1 C^T bf16 (VhT); 2 split hi/lo+relu+bias
//  (K'=1536: AhBh/AhBl/AlBh, 16 steps each); 3 C f32 (A bf16 pre-swizzled).
// ---------------------------------------------------------------------------
struct GEMMDesc {
    const float* Af;
    const bf16* Ab;
    const bf16* B0;
    const bf16* B1;
    const float* bias;
    bf16* Cb;
    bf16* Cl;
    float* Cf;
    int mode;
    float cscale;
};
struct G4 { GEMMDesc d[4]; };

__global__ __launch_bounds__(256, 3) void gemm128(G4 gg) {
    __shared__ bf16 sm[16384];   // 2 bufs x (As[128][32] | Bs[128][32])

    const GEMMDesc g = gg.d[blockIdx.z];
    const int mode = g.mode;
    const int mbase = blockIdx.x * 128, nbase = blockIdx.y * 128;
    const int t = threadIdx.x, w = t >> 6, l = t & 63;
    const int quad = l >> 4, c = l & 15;
    const int wr = w >> 1, wc = w & 1;

    const v4f zero4 = {0.f, 0.f, 0.f, 0.f};
    v4f acc[4][4];
#pragma unroll
    for (int m = 0; m < 4; ++m)
#pragma unroll
        for (int nn = 0; nn < 4; ++nn) acc[m][nn] = zero4;

    const int nsteps = (mode == 2) ? 48 : 16;
    const int off = ((quad ^ (c & 3)) << 3);      // loop-invariant frag offset
    const int arw = t >> 1;                       // A stage row 0..127
    const int ach = t & 1;                        // A stage col half
    const int brow = l >> 2, bch8 = (l & 3) * 8;  // B stage lane mapping

    float4 aA[4], aB[4];                          // A f32 prefetch (16 floats)

    auto issue = [&](int s, bf16* As, bf16* Bs, float4 (&ar)[4]) {
        const bf16* Bsrc = (mode == 2 && ((s >> 4) == 1)) ? g.B1 : g.B0;
        const int k0 = (mode == 2) ? (s & 15) * 32 : s * 32;
#pragma unroll
        for (int j = 0; j < 2; ++j) {
            int rg = (w * 2 + j) * 16;
            gload_lds16(Bsrc + (long)(nbase + rg + brow) * 512 + k0 + bch8,
                        Bs + rg * 32);
        }
        if (mode == 3) {
#pragma unroll
            for (int j = 0; j < 2; ++j) {
                int rg = (w * 2 + j) * 16;
                gload_lds16(g.Ab + (long)(mbase + rg + brow) * 512 + k0 + bch8,
                            As + rg * 32);
            }
        } else {
            const float* p = g.Af + (long)(mbase + arw) * 512 + k0 + ach * 16;
            ar[0] = *(const float4*)p;
            ar[1] = *(const float4*)(p + 4);
            ar[2] = *(const float4*)(p + 8);
            ar[3] = *(const float4*)(p + 12);
        }
    };

    auto writeA = [&](int s, bf16* As, const float4 (&ar)[4]) {
        if (mode == 3) return;
        const bool lo = (mode == 2) && ((s >> 4) == 2);
        float v[16] = {ar[0].x, ar[0].y, ar[0].z, ar[0].w,
                       ar[1].x, ar[1].y, ar[1].z, ar[1].w,
                       ar[2].x, ar[2].y, ar[2].z, ar[2].w,
                       ar[3].x, ar[3].y, ar[3].z, ar[3].w};
#pragma unroll
        for (int u = 0; u < 2; ++u) {
            bfx8 hv;
            if (!lo) {
#pragma unroll
                for (int q = 0; q < 8; ++q) hv[q] = (bf16)v[u * 8 + q];
            } else {
#pragma unroll
                for (int q = 0; q < 8; ++q) {
                    bf16 h = (bf16)v[u * 8 + q];
                    hv[q] = (bf16)(v[u * 8 + q] - (float)h);
                }
            }
            const int ch = (ach * 2 + u) ^ (arw & 3);
            *(bfx8*)(&As[arw * 32 + ch * 8]) = hv;
        }
    };

    auto compute = [&](const bf16* As, const bf16* Bs) {
        bfx8 af[4], bb[4];
#pragma unroll
        for (int m = 0; m < 4; ++m)
            af[m] = *(const bfx8*)(&As[(wr * 64 + m * 16 + c) * 32 + off]);
#pragma unroll
        for (int nn = 0; nn < 4; ++nn)
            bb[nn] = *(const bfx8*)(&Bs[(wc * 64 + nn * 16 + c) * 32 + off]);
#pragma unroll
        for (int m = 0; m < 4; ++m)
#pragma unroll
            for (int nn = 0; nn < 4; ++nn)
                acc[m][nn] = mfma16(af[m], bb[nn], acc[m][nn]);
    };

    bf16* buf0 = sm;
    bf16* buf1 = sm + 8192;
    // buf layout: As = buf, Bs = buf + 4096
    issue(0, buf0, buf0 + 4096, aA);
    writeA(0, buf0, aA);
    __syncthreads();
    for (int s = 0; s < nsteps; s += 2) {
        issue(s + 1, buf1, buf1 + 4096, aB);
        compute(buf0, buf0 + 4096);
        writeA(s + 1, buf1, aB);
        __syncthreads();
        const bool more = (s + 2 < nsteps);
        if (more) issue(s + 2, buf0, buf0 + 4096, aA);
        compute(buf1, buf1 + 4096);
        if (more) writeA(s + 2, buf0, aA);
        __syncthreads();
    }

    // ---- epilogues
    if (mode == 3) {
        float* C = g.Cf;
#pragma unroll
        for (int m = 0; m < 4; ++m)
#pragma unroll
            for (int nn = 0; nn < 4; ++nn)
#pragma unroll
                for (int i = 0; i < 4; ++i) {
                    int row = mbase + wr * 64 + m * 16 + quad * 4 + i;
                    int col = nbase + wc * 64 + nn * 16 + c;
                    C[(long)row * 512 + col] = acc[m][nn][i];
                }
        return;
    }

    if (mode == 1) {
        bf16* CT = g.Cb + ((long)(mbase >> 9)) * 262144;
        const int s0 = mbase & 511;
        for (int h = 0; h < 2; ++h) {
            if (wr == h) {
#pragma unroll
                for (int m = 0; m < 4; ++m)
#pragma unroll
                    for (int nn = 0; nn < 4; ++nn)
#pragma unroll
                        for (int i = 0; i < 4; ++i)
                            sm[(wc * 64 + nn * 16 + c) * 64 + m * 16 + quad * 4 + i] =
                                (bf16)acc[m][nn][i];
            }
            __syncthreads();
            {
                const bf16* src = sm + (t >> 1) * 64 + (t & 1) * 32;
                bf16* d = CT + (long)(nbase + (t >> 1)) * 512 + s0 + h * 64 + (t & 1) * 32;
#pragma unroll
                for (int j = 0; j < 4; ++j) *(bfx8*)(d + j * 8) = *(const bfx8*)(src + j * 8);
            }
            __syncthreads();
        }
        return;
    }

    // modes 0 / 2: row-major bf16 via LDS pack
    for (int h = 0; h < 2; ++h) {
        if (wr == h) {
#pragma unroll
            for (int m = 0; m < 4; ++m)
#pragma unroll
                for (int nn = 0; nn < 4; ++nn)
#pragma unroll
                    for (int i = 0; i < 4; ++i) {
                        int col = wc * 64 + nn * 16 + c;
                        float v = acc[m][nn][i];
                        if (mode == 2) v = fmaxf(v + g.bias[nbase + col], 0.f);
                        else v *= g.cscale;
                        bf16 hv = (bf16)v;
                        sm[(m * 16 + quad * 4 + i) * 128 + col] = hv;
                        if (mode == 2)
                            sm[8192 + (m * 16 + quad * 4 + i) * 128 + col] =
                                (bf16)(v - (float)hv);
                    }
        }
        __syncthreads();
        {
            const int row = t >> 2, seg = t & 3;
            const bf16* src = sm + row * 128 + seg * 32;
            bf16* d = g.Cb + (long)(mbase + h * 64 + row) * 512 + nbase + seg * 32;
#pragma unroll
            for (int j = 0; j < 4; ++j) *(bfx8*)(d + j * 8) = *(const bfx8*)(src + j * 8);
            if (mode == 2) {
                const bf16* src2 = sm + 8192 + row * 128 + seg * 32;
                bf16* d2 = g.Cl + (long)(mbase + h * 64 + row) * 512 + nbase + seg * 32;
#pragma unroll
                for (int j = 0; j < 4; ++j) *(bfx8*)(d2 + j * 8) = *(const bfx8*)(src2 + j * 8);
            }
        }
        __syncthreads();
    }
}

// ---------------------------------------------------------------------------
// Fused GRU (R12): LDS-staged weights, split Xg + split hp, fast tanh.
// ---------------------------------------------------------------------------
__global__ __launch_bounds__(256) void gru_fused_kernel(
    const bf16* __restrict__ Xh, const bf16* __restrict__ Xl,
    const float* __restrict__ hp,
    const bf16* __restrict__ wih, const bf16* __restrict__ wil,
    const bf16* __restrict__ whh, const bf16* __restrict__ whl,
    const float* __restrict__ gbi, const float* __restrict__ gbh,
    const float* __restrict__ pa, const float* __restrict__ Wsigma,
    const float* __restrict__ Wrho,
    const float* __restrict__ lenv, const float* __restrict__ stepv,
    float* __restrict__ muv, float* __restrict__ sigv) {
    __shared__ bf16 Wh[192][72], Wl[192][72];
    __shared__ float biL[384];

    const int b = blockIdx.x;
    const int qb = b & 7, nh = b >> 3, hd = nh & 7, n = nh >> 3;
    const int t = threadIdx.x;
    const int w = t >> 6, lane = t & 63, quad = lane >> 4, c = lane & 15;
    const int q0 = qb * 64 + w * 16;

    if (t < 192) { biL[t] = gbi[t]; biL[192 + t] = gbh[t]; }
#pragma unroll
    for (int it = 0; it < 6; ++it) {
        int task = it * 256 + t;
        int r = task >> 3, ch = task & 7;
        *(bfx8*)(&Wh[r][ch * 8]) = *(const bfx8*)(wih + r * 64 + ch * 8);
        *(bfx8*)(&Wl[r][ch * 8]) = *(const bfx8*)(wil + r * 64 + ch * 8);
    }
    __syncthreads();

    const v4f zero4 = {0.f, 0.f, 0.f, 0.f};
    v4f gi[12], gh[12];
#pragma unroll
    for (int nt = 0; nt < 12; ++nt) gi[nt] = zero4;
#pragma unroll
    for (int ks = 0; ks < 2; ++ks) {
        long ao = (long)(n * 512 + q0 + c) * 512 + hd * 64 + ks * 32 + quad * 8;
        bfx8 xh = *(const bfx8*)(Xh + ao);
        bfx8 xl = *(const bfx8*)(Xl + ao);
#pragma unroll
        for (int nt = 0; nt < 12; ++nt) {
            bfx8 bh = *(const bfx8*)(&Wh[nt * 16 + c][ks * 32 + quad * 8]);
            bfx8 bl = *(const bfx8*)(&Wl[nt * 16 + c][ks * 32 + quad * 8]);
            gi[nt] = mfma16(xh, bh, gi[nt]);
            gi[nt] = mfma16(xh, bl, gi[nt]);
            gi[nt] = mfma16(xl, bh, gi[nt]);
        }
    }
    __syncthreads();
#pragma unroll
    for (int it = 0; it < 6; ++it) {
        int task = it * 256 + t;
        int r = task >> 3, ch = task & 7;
        *(bfx8*)(&Wh[r][ch * 8]) = *(const bfx8*)(whh + r * 64 + ch * 8);
        *(bfx8*)(&Wl[r][ch * 8]) = *(const bfx8*)(whl + r * 64 + ch * 8);
    }
    __syncthreads();
#pragma unroll
    for (int nt = 0; nt < 12; ++nt) gh[nt] = zero4;
#pragma unroll
    for (int ks = 0; ks < 2; ++ks) {
        bfx8 ah, al;
        split8(hp + (long)(nh * 512 + q0 + c) * 64 + ks * 32 + quad * 8, ah, al);
#pragma unroll
        for (int nt = 0; nt < 12; ++nt) {
            bfx8 bh = *(const bfx8*)(&Wh[nt * 16 + c][ks * 32 + quad * 8]);
            bfx8 bl = *(const bfx8*)(&Wl[nt * 16 + c][ks * 32 + quad * 8]);
            gh[nt] = mfma16(ah, bh, gh[nt]);
            gh[nt] = mfma16(ah, bl, gh[nt]);
            gh[nt] = mfma16(al, bh, gh[nt]);
        }
    }

    float st[4][4];
#pragma unroll
    for (int t4 = 0; t4 < 4; ++t4) {
        float bir = biL[t4 * 16 + c];
        float biz = biL[64 + t4 * 16 + c];
        float bin = biL[128 + t4 * 16 + c];
        float bhr = biL[192 + t4 * 16 + c];
        float bhz = biL[256 + t4 * 16 + c];
        float bhn = biL[320 + t4 * 16 + c];
#pragma unroll
        for (int i = 0; i < 4; ++i) {
            int row = q0 + quad * 4 + i;
            float r = sigm(gi[t4][i] + bir + gh[t4][i] + bhr);
            float z = sigm(gi[t4 + 4][i] + biz + gh[t4 + 4][i] + bhz);
            float nn_ = tanh_fast(gi[t4 + 8][i] + bin + r * (gh[t4 + 8][i] + bhn));
            float hpv = hp[(long)(nh * 512 + row) * 64 + t4 * 16 + c];
            st[t4][i] = (1.0f - z) * nn_ + z * hpv;
        }
    }

    float ws_[4], wr0[4], wr1[4], wr2[4];
#pragma unroll
    for (int t4 = 0; t4 < 4; ++t4) {
        int d = t4 * 16 + c;
        ws_[t4] = Wsigma[hd * 64 + d];
        wr0[t4] = Wrho[(hd * 64 + d) * 3 + 0];
        wr1[t4] = Wrho[(hd * 64 + d) * 3 + 1];
        wr2[t4] = Wrho[(hd * 64 + d) * 3 + 2];
    }
#pragma unroll
    for (int i = 0; i < 4; ++i) {
        float s0 = 0.f, s1 = 0.f, s2 = 0.f, s3 = 0.f;
#pragma unroll
        for (int t4 = 0; t4 < 4; ++t4) {
            float sv = st[t4][i];
            s0 += sv * ws_[t4];
            s1 += sv * wr0[t4];
            s2 += sv * wr1[t4];
            s3 += sv * wr2[t4];
        }
#pragma unroll
        for (int o = 1; o < 16; o <<= 1) {
            s0 += __shfl_xor(s0, o);
            s1 += __shfl_xor(s1, o);
            s2 += __shfl_xor(s2, o);
            s3 += __shfl_xor(s3, o);
        }
        if (c == 0) {
            int row = q0 + quad * 4 + i;
            int idx = nh * 512 + row, rq = n * 512 + row;
            float L = lenv[rq], sp = stepv[rq];
            float sg = (fmaxf(s0, 0.f) + 0.27f) / L;
            float fl = floorf(s1);
            float steps = fl + sigm(10.0f * (fabsf(s1 - fl) - 0.5f));
            float ag = sigm(s2), bg = sigm(s3);
            float mu_ = steps * sp + ag * pa[idx] + bg;
            float mu = fmaxf(0.01f * mu_, fminf(mu_, 1.0f + 0.01f * mu_));
            muv[idx] = mu;
            sigv[idx] = sg;
        }
    }
}

// ---------------------------------------------------------------------------
// Fused attention (R14): single barrier; MFMA row-sums; exp2-direct.
// att stored PRE-SWIZZLED for BK=32 gemm: col ^ ((row&3)<<3).
// ---------------------------------------------------------------------------
__global__ __launch_bounds__(256) void attn_fused_kernel(
    const bf16* __restrict__ Qh, const bf16* __restrict__ Kh,
    const bf16* __restrict__ VhT, const unsigned* __restrict__ mpack,
    const float* __restrict__ vpos, const float* __restrict__ mixv,
    const float* __restrict__ stepv, const float* __restrict__ muv,
    const float* __restrict__ sigv, bf16* __restrict__ att) {
    __shared__ bf16 Pp[16][520];
    __shared__ bf16 Pg[16][520];

    const int b = blockIdx.x;
    const int nh = ((b >> 8) << 3) | (b & 7);
    const int qt = (b >> 3) & 31;
    const int hd = nh & 7, n = nh >> 3;
    const int t = threadIdx.x;
    const int wave = t >> 6, lane = t & 63;
    const int quad = lane >> 4, c = lane & 15;
    const int qloc = quad * 4;

    const bf16* qrow = Qh + (long)(n * 512 + qt * 16 + c) * 512 + hd * 64 + quad * 8;
    bfx8 afr0 = *(const bfx8*)qrow;
    bfx8 afr1 = *(const bfx8*)(qrow + 32);

    const v4f zero4 = {0.f, 0.f, 0.f, 0.f};
    v4f acc[8];
#pragma unroll
    for (int i = 0; i < 8; ++i) acc[i] = zero4;

    const bf16* kbase = Kh + (long)(n * 512 + wave * 128 + c) * 512 + hd * 64 + quad * 8;
#pragma unroll
    for (int t8 = 0; t8 < 8; ++t8) {
        bfx8 b0 = *(const bfx8*)(kbase + (long)t8 * 16 * 512);
        bfx8 b1 = *(const bfx8*)(kbase + (long)t8 * 16 * 512 + 32);
        acc[t8] = mfma16(afr0, b0, acc[t8]);
        acc[t8] = mfma16(afr1, b1, acc[t8]);
    }

    float mu_[4], c2n[4], stp[4];
#pragma unroll
    for (int i = 0; i < 4; ++i) {
        int q = qt * 16 + qloc + i;
        int idx = nh * 512 + q, rq = n * 512 + q;
        mu_[i] = muv[idx];
        float sg = sigv[idx];
        c2n[i] = -0.72134752f / (sg * sg);   // -0.5*log2(e)/sigma^2
        stp[i] = stepv[rq];
    }

    const unsigned mb32 = mpack[(long)(n * 32 + qt) * 256 + t];
    unsigned mbits[4];
#pragma unroll
    for (int i = 0; i < 4; ++i) mbits[i] = (mb32 >> (8 * i)) & 0xffu;

    float vp[8];
#pragma unroll
    for (int t8 = 0; t8 < 8; ++t8) vp[t8] = vpos[wave * 128 + t8 * 16 + c];

#pragma unroll
    for (int i = 0; i < 4; ++i) {
        float m = mu_[i], s = stp[i], cg = c2n[i];
#pragma unroll
        for (int t8 = 0; t8 < 8; ++t8) {
            int on = (mbits[i] >> t8) & 1;
            float pv = on ? __builtin_amdgcn_exp2f(acc[t8][i]) : 0.f;
            float d = vp[t8] * s - m;
            float gv = on ? __builtin_amdgcn_exp2f(d * d * cg) : 0.f;
            int k = wave * 128 + t8 * 16 + c;
            Pp[qloc + i][k] = (bf16)pv;
            Pg[qloc + i][k] = (bf16)gv;
        }
    }

    __syncthreads();  // the ONLY barrier

    bfx8 ones;
#pragma unroll
    for (int j = 0; j < 8; ++j) ones[j] = (bf16)1.0f;

    v4f accP = zero4, accG = zero4, accS = zero4, accT = zero4;
    const bf16* vrow = VhT + (long)(n * 512 + hd * 64 + wave * 16 + c) * 512 + quad * 8;
    __builtin_amdgcn_s_setprio(1);
#pragma unroll
    for (int ks = 0; ks < 16; ++ks) {
        bfx8 bf_ = *(const bfx8*)(vrow + ks * 32);
        bfx8 ap = *(const bfx8*)(&Pp[c][ks * 32 + quad * 8]);
        bfx8 ag = *(const bfx8*)(&Pg[c][ks * 32 + quad * 8]);
        accP = mfma16(ap, bf_, accP);
        accG = mfma16(ag, bf_, accG);
        accS = mfma16(ap, ones, accS);
        accT = mfma16(ag, ones, accT);
    }
    __builtin_amdgcn_s_setprio(0);

#pragma unroll
    for (int i = 0; i < 4; ++i) {
        float Sp = accS[i];
        float Sg = accT[i] + 512.0f * 1e-20f;
        float m_ = mixv[n * 512 + qt * 16 + qloc + i];
        float aci = (1.0f - m_) / Sp;
        float bci = m_ / Sg;
        int q = qt * 16 + quad * 4 + i;
        // pre-swizzle for BK=32 gemm mode-3: row&3 == i here
        int cx = (wave * 16 + c) ^ (i << 3);
        att[(long)(n * 512 + q) * 512 + hd * 64 + cx] =
            (bf16)(aci * accP[i] + bci * accG[i]);
    }
}

// ---------------------------------------------------------------------------
extern "C" void kernel_launch(void* const* d_in, const int* in_sizes, int n_in,
                              void* d_out, int out_size, void* d_ws, size_t ws_size,
                              hipStream_t stream) {
    (void)in_sizes; (void)n_in; (void)out_size; (void)ws_size;

    const float* Q = (const float*)d_in[0];
    const float* K = (const float*)d_in[1];
    const float* V = (const float*)d_in[2];
    const float* past_state = (const float*)d_in[3];
    const float* past_att = (const float*)d_in[4];
    const float* vpos = (const float*)d_in[5];
    const int* mask = (const int*)d_in[6];
    const float* Wq = (const float*)d_in[7];
    const float* Wk = (const float*)d_in[8];
    const float* Wv = (const float*)d_in[9];
    const float* Wpos = (const float*)d_in[10];
    const float* bpos = (const float*)d_in[11];
    const float* Wsigma = (const float*)d_in[12];
    const float* Wrho = (const float*)d_in[13];
    const float* mix_w = (const float*)d_in[14];
    const float* mix_b = (const float*)d_in[15];
    const float* gwi = (const float*)d_in[16];
    const float* gwh = (const float*)d_in[17];
    const float* gbi = (const float*)d_in[18];
    const float* gbh = (const float*)d_in[19];
    const float* Wc = (const float*)d_in[20];
    float* out = (float*)d_out;

    // ---- workspace ----
    char* p = (char*)d_ws;
    const size_t SZB = 8192UL * 512 * 2;
    const size_t SZW = 512UL * 512 * 2;
    bf16* WqT = (bf16*)p;   p += SZW;
    bf16* WkT = (bf16*)p;   p += SZW;
    bf16* WvT = (bf16*)p;   p += SZW;
    bf16* WpT = (bf16*)p;   p += SZW;
    bf16* WpTl = (bf16*)p;  p += SZW;
    bf16* WcT = (bf16*)p;   p += SZW;
    bf16* wih = (bf16*)p;   p += 24576;
    bf16* wil = (bf16*)p;   p += 24576;
    bf16* whh = (bf16*)p;   p += 24576;
    bf16* whl = (bf16*)p;   p += 24576;
    bf16* Qh = (bf16*)p;    p += SZB;
    bf16* Kh = (bf16*)p;    p += SZB;
    bf16* VhT = (bf16*)p;   p += SZB;
    bf16* Xh = (bf16*)p;
    bf16* att = Xh;         p += SZB;
    bf16* Xl = (bf16*)p;    p += SZB;
    unsigned* mpack = (unsigned*)p;      p += 16UL * 32 * 256 * 4;
    float* mixv = (float*)p;  p += 32768;
    float* stepv = (float*)p; p += 32768;
    float* lenv = (float*)p;  p += 32768;
    float* muv = (float*)p;   p += 262144;
    float* sigv = (float*)p;  p += 262144;

    dim3 blk(256);

    PrepArgs pa;
    pa.wsrc[0] = Wq; pa.wsrc[1] = Wk; pa.wsrc[2] = Wv; pa.wsrc[3] = Wpos; pa.wsrc[4] = Wc;
    pa.wdst[0] = WqT; pa.wdst[1] = WkT; pa.wdst[2] = WvT; pa.wdst[3] = WpT; pa.wdst[4] = WcT;
    pa.wdstlo[0] = nullptr; pa.wdstlo[1] = nullptr; pa.wdstlo[2] = nullptr;
    pa.wdstlo[3] = WpTl; pa.wdstlo[4] = nullptr;
    pa.gwi = gwi; pa.gwh = gwh;
    pa.wih = wih; pa.wil = wil; pa.whh = whh; pa.whl = whl;
    pa.Q = Q; pa.mask = mask; pa.mix_w = mix_w; pa.mix_b = mix_b;
    pa.mixv = mixv; pa.stepv = stepv; pa.lenv = lenv; pa.mpack = mpack;
    prep_kernel<<<dim3(834), blk, 0, stream>>>(pa);

    // projections: d[0]=split (longest, z=0 first), d[1]=Q (cscale for exp2),
    // d[2]=K, d[3]=V(T)
    G4 gp;
    gp.d[0].Af = Q;  gp.d[0].Ab = nullptr; gp.d[0].B0 = WpT; gp.d[0].B1 = WpTl;
    gp.d[0].bias = bpos; gp.d[0].Cb = Xh; gp.d[0].Cl = Xl; gp.d[0].Cf = nullptr;
    gp.d[0].mode = 2; gp.d[0].cscale = 1.0f;
    gp.d[1].Af = Q;  gp.d[1].Ab = nullptr; gp.d[1].B0 = WqT; gp.d[1].B1 = nullptr;
    gp.d[1].bias = nullptr; gp.d[1].Cb = Qh; gp.d[1].Cl = nullptr; gp.d[1].Cf = nullptr;
    gp.d[1].mode = 0; gp.d[1].cscale = 0.125f * 1.44269504089f;
    gp.d[2].Af = K;  gp.d[2].Ab = nullptr; gp.d[2].B0 = WkT; gp.d[2].B1 = nullptr;
    gp.d[2].bias = nullptr; gp.d[2].Cb = Kh; gp.d[2].Cl = nullptr; gp.d[2].Cf = nullptr;
    gp.d[2].mode = 0; gp.d[2].cscale = 1.0f;
    gp.d[3].Af = V;  gp.d[3].Ab = nullptr; gp.d[3].B0 = WvT; gp.d[3].B1 = nullptr;
    gp.d[3].bias = nullptr; gp.d[3].Cb = VhT; gp.d[3].Cl = nullptr; gp.d[3].Cf = nullptr;
    gp.d[3].mode = 1; gp.d[3].cscale = 1.0f;
    gemm128<<<dim3(64, 4, 4), blk, 0, stream>>>(gp);

    gru_fused_kernel<<<dim3(1024), blk, 0, stream>>>(
        Xh, Xl, past_state, wih, wil, whh, whl, gbi, gbh, past_att, Wsigma, Wrho,
        lenv, stepv, muv, sigv);

    attn_fused_kernel<<<dim3(4096), blk, 0, stream>>>(
        Qh, Kh, VhT, mpack, vpos, mixv, stepv, muv, sigv, att);

    G4 go;
    go.d[0].Af = nullptr; go.d[0].Ab = att; go.d[0].B0 = WcT; go.d[0].B1 = nullptr;
    go.d[0].bias = nullptr; go.d[0].Cb = nullptr; go.d[0].Cl = nullptr; go.d[0].Cf = out;
    go.d[0].mode = 3; go.d[0].cscale = 1.0f;
    go.d[1] = go.d[0]; go.d[2] = go.d[0]; go.d[3] = go.d[0];  // unused
    gemm128<<<dim3(64, 4, 1), blk, 0, stream>>>(go);
}

// Round 8
// 323.339 us; speedup vs baseline: 1.1444x; 1.0541x over previous
//
#include <hip/hip_runtime.h>

// ---------------------------------------------------------------------------
// Multiheaded_GRUMix_Attention on MI355X (gfx950). Inputs f32, output f32.
//
// R17:
//  - gemm128 reverted to R14-exact (BK=64 2-phase dbuf, f32-A reg-stage,
//    gload_lds B from pre-swizzled weights, 2 blocks/CU). BK=32 experiment
//    regressed (6.7M bank conflicts, worse coalescing) and proved occupancy
//    wasn't LDS-limited there.
//  - attn: Pp/Pg pad (520) replaced by XOR swizzle k^((row&7)<<3) ->
//    LDS exactly 32768 B -> 5 blocks/CU (was 4 at 33792);
//    __launch_bounds__(256,5). attn IS latency-bound at 37% occupancy.
// gru = R12 LDS version; prep/mpack = R13/R14.
// ---------------------------------------------------------------------------

typedef __bf16 bf16;
typedef __bf16 bfx8 __attribute__((ext_vector_type(8)));
typedef float v4f __attribute__((ext_vector_type(4)));

__device__ inline float sigm(float x) { return 1.0f / (1.0f + __expf(-x)); }
__device__ inline float tanh_fast(float x) { return 1.0f - 2.0f / (__expf(2.0f * x) + 1.0f); }

__device__ inline v4f mfma16(bfx8 a, bfx8 b, v4f c) {
    return __builtin_amdgcn_mfma_f32_16x16x32_bf16(a, b, c, 0, 0, 0);
}

typedef const __attribute__((address_space(1))) void* gvp;
typedef __attribute__((address_space(3))) void* lvp;

__device__ inline void gload_lds16(const bf16* g, bf16* l) {
    __builtin_amdgcn_global_load_lds((gvp)g, (lvp)l, 16, 0, 0);
}

__device__ inline void split8(const float* __restrict__ p, bfx8& hi, bfx8& lo) {
    float4 x = *(const float4*)p;
    float4 y = *(const float4*)(p + 4);
    float v[8] = {x.x, x.y, x.z, x.w, y.x, y.y, y.z, y.w};
#pragma unroll
    for (int j = 0; j < 8; ++j) {
        bf16 h = (bf16)v[j];
        hi[j] = h;
        lo[j] = (bf16)(v[j] - (float)h);
    }
}

// ---------------------------------------------------------------------------
// prep_kernel roles:
//  [0,320)    trans_w: bf16 W^T[col][k'], k' = k ^ ((col&7)<<3)  (BK=64 swz)
//  [320,322)  gru weights -> [192][64] hi/lo
//  [322,834)  mix gate + lengths + mpack
// ---------------------------------------------------------------------------
struct PrepArgs {
    const float* wsrc[5]; bf16* wdst[5]; bf16* wdstlo[5];
    const float* gwi; const float* gwh;
    bf16* wih; bf16* wil; bf16* whh; bf16* whl;
    const float* Q; const int* mask; const float* mix_w; const float* mix_b;
    float* mixv; float* stepv; float* lenv; unsigned* mpack;
};

__global__ __launch_bounds__(256) void prep_kernel(PrepArgs a) {
    __shared__ __align__(16) char smraw[17408];
    const int b = blockIdx.x;
    const int t = threadIdx.x;

    if (b < 320) {
        float (*tile)[68] = (float(*)[68])smraw;
        const int wy = b >> 6, bx = b & 63;
        const float* src = a.wsrc[wy];
        bf16* dst = a.wdst[wy];
        bf16* dlo = a.wdstlo[wy];
        const int rbase = (bx >> 3) * 64, cbase = (bx & 7) * 64;
        const int r = t >> 2, cc = (t & 3) * 16;
        {
            const float* p = src + (long)(rbase + r) * 512 + cbase + cc;
            *(float4*)(&tile[r][cc]) = *(const float4*)p;
            *(float4*)(&tile[r][cc + 4]) = *(const float4*)(p + 4);
            *(float4*)(&tile[r][cc + 8]) = *(const float4*)(p + 8);
            *(float4*)(&tile[r][cc + 12]) = *(const float4*)(p + 12);
        }
        __syncthreads();
        bfx8 h0, h1, l0, l1;
#pragma unroll
        for (int j = 0; j < 8; ++j) {
            float v0 = tile[cc + j][r];
            float v1 = tile[cc + 8 + j][r];
            bf16 a0 = (bf16)v0, a1 = (bf16)v1;
            h0[j] = a0; l0[j] = (bf16)(v0 - (float)a0);
            h1[j] = a1; l1[j] = (bf16)(v1 - (float)a1);
        }
        const int n_ = cbase + r;
        const int x_ = (n_ & 7) << 3;
        const long rowo = (long)n_ * 512;
        const int ka = (rbase + cc) ^ x_;
        const int kb = (rbase + cc + 8) ^ x_;
        *(bfx8*)(dst + rowo + ka) = h0;
        *(bfx8*)(dst + rowo + kb) = h1;
        if (dlo) {
            *(bfx8*)(dlo + rowo + ka) = l0;
            *(bfx8*)(dlo + rowo + kb) = l1;
        }
        return;
    }

    if (b < 322) {
        const int m = b - 320;
        const float* src = m ? a.gwh : a.gwi;
        bf16* dh = m ? a.whh : a.wih;
        bf16* dl = m ? a.whl : a.wil;
        for (int e = t; e < 12288; e += 256) {
            int n_ = e >> 6, k = e & 63;
            float v = src[k * 192 + n_];
            bf16 h = (bf16)v;
            dh[e] = h;
            dl[e] = (bf16)(v - (float)h);
        }
        return;
    }

    unsigned (*mwords)[16] = (unsigned(*)[16])smraw;
    const int bm = b - 322;
    const int qt = bm & 31, n = bm >> 5;
    const int wave = t >> 6, lane = t & 63;
#pragma unroll
    for (int rr = 0; rr < 4; ++rr) {
        const int rloc = wave * 4 + rr;
        const long row = (long)n * 512 + qt * 16 + rloc;
        float dot = 0.f, ms = 0.f;
        unsigned myw = 0;
#pragma unroll
        for (int j = 0; j < 8; ++j) {
            float qv = a.Q[row * 512 + j * 64 + lane];
            float wv = a.mix_w[j * 64 + lane];
            dot += qv * wv;
            int mv = a.mask[row * 512 + j * 64 + lane];
            unsigned long long bl = __ballot(mv != 0);
            ms += (float)__popcll(bl);
            if ((lane >> 1) == j) myw = (unsigned)(bl >> ((lane & 1) * 32));
        }
#pragma unroll
        for (int o = 32; o > 0; o >>= 1) dot += __shfl_xor(dot, o);
        if (lane < 16) mwords[rloc][lane] = myw;
        if (lane == 0) {
            a.mixv[row] = sigm(dot + a.mix_b[0]);
            a.lenv[row] = ms;
            a.stepv[row] = 1.0f / fmaxf(1.0f, ms - 1.0f);
        }
    }
    __syncthreads();
    {
        const int quad = (lane >> 4), c = lane & 15;
        unsigned out = 0;
#pragma unroll
        for (int i = 0; i < 4; ++i) {
            const int rl = quad * 4 + i;
            unsigned w0 = mwords[rl][wave * 4 + 0];
            unsigned w1 = mwords[rl][wave * 4 + 1];
            unsigned w2 = mwords[rl][wave * 4 + 2];
            unsigned w3 = mwords[rl][wave * 4 + 3];
            unsigned byte_ = ((w0 >> c) & 1u) | (((w0 >> (16 + c)) & 1u) << 1) |
                             (((w1 >> c) & 1u) << 2) | (((w1 >> (16 + c)) & 1u) << 3) |
                             (((w2 >> c) & 1u) << 4) | (((w2 >> (16 + c)) & 1u) << 5) |
                             (((w3 >> c) & 1u) << 6) | (((w3 >> (16 + c)) & 1u) << 7);
            out |= byte_ << (8 * i);
        }
        a.mpack[(long)bm * 256 + t] = out;
    }
}

// ---------------------------------------------------------------------------
// Unified 128x128 GEMM, BK=64, 2-phase double-buffered (R14-exact). modes:
//  0: C bf16 [M][512] (*cscale); 1: C^T bf16 (VhT);
//  2: split hi/lo + relu+bias (K'=1536); 3: C f32 (A pre-swizzled bf16).
// ---------------------------------------------------------------------------
struct GEMMDesc {
    const float* Af;
    const bf16* Ab;
    const bf16* B0;
    const bf16* B1;
    const float* bias;
    bf16* Cb;
    bf16* Cl;
    float* Cf;
    int mode;
    float cscale;
};
struct G4 { GEMMDesc d[4]; };

__global__ __launch_bounds__(256, 2) void gemm128(G4 gg) {
    __shared__ bf16 sm[32768];   // 2 bufs x (As[128][64] | Bs[128][64])

    const GEMMDesc g = gg.d[blockIdx.z];
    const int mode = g.mode;
    const int mbase = blockIdx.x * 128, nbase = blockIdx.y * 128;
    const int t = threadIdx.x, w = t >> 6, l = t & 63;
    const int quad = l >> 4, c = l & 15;
    const int wr = w >> 1, wc = w & 1;

    const v4f zero4 = {0.f, 0.f, 0.f, 0.f};
    v4f acc[4][4];
#pragma unroll
    for (int m = 0; m < 4; ++m)
#pragma unroll
        for (int nn = 0; nn < 4; ++nn) acc[m][nn] = zero4;

    const int nsteps = (mode == 2) ? 24 : 8;
    const int arow_t = t >> 3;
    const int ach = t & 7;
    const int asw = ((ach ^ (arow_t & 7)) * 8);
    const int xm = c & 7;
    const int slot0 = w * 4;
    const int srow = l >> 3;
    const int sch8 = (l & 7) * 8;

    float4 ax[4], ay[4];

    auto issue = [&](int s, bf16* As, bf16* Bs) {
        const bf16* Bsrc = g.B0;
        int k0;
        if (mode == 2) {
            int ph = s >> 3;
            k0 = (s & 7) * 64;
            if (ph == 1) Bsrc = g.B1;
        } else {
            k0 = s * 64;
        }
#pragma unroll
        for (int j = 0; j < 4; ++j) {
            int sl = slot0 + j;
            int row = sl * 8 + srow;
            gload_lds16(Bsrc + (long)(nbase + row) * 512 + k0 + sch8, Bs + sl * 512);
        }
        if (mode == 3) {
#pragma unroll
            for (int j = 0; j < 4; ++j) {
                int sl = slot0 + j;
                int row = sl * 8 + srow;
                gload_lds16(g.Ab + (long)(mbase + row) * 512 + k0 + sch8, As + sl * 512);
            }
        } else {
#pragma unroll
            for (int j = 0; j < 4; ++j) {
                const float* p = g.Af + (long)(mbase + j * 32 + arow_t) * 512 + k0 + ach * 8;
                ax[j] = *(const float4*)p;
                ay[j] = *(const float4*)(p + 4);
            }
        }
    };

    auto writeA = [&](int s, bf16* As) {
        if (mode == 3) return;
        const bool lo = (mode == 2) && ((s >> 3) == 2);
#pragma unroll
        for (int j = 0; j < 4; ++j) {
            float v[8] = {ax[j].x, ax[j].y, ax[j].z, ax[j].w,
                          ay[j].x, ay[j].y, ay[j].z, ay[j].w};
            bfx8 hv;
            if (!lo) {
#pragma unroll
                for (int q = 0; q < 8; ++q) hv[q] = (bf16)v[q];
            } else {
#pragma unroll
                for (int q = 0; q < 8; ++q) {
                    bf16 h = (bf16)v[q];
                    hv[q] = (bf16)(v[q] - (float)h);
                }
            }
            *(bfx8*)(&As[(j * 32 + arow_t) * 64 + asw]) = hv;
        }
    };

    auto compute = [&](const bf16* As, const bf16* Bs) {
#pragma unroll
        for (int ks = 0; ks < 2; ++ks) {
            const int off = (((ks * 4 + quad) ^ xm) * 8);
            bfx8 af[4], bb[4];
#pragma unroll
            for (int m = 0; m < 4; ++m)
                af[m] = *(const bfx8*)(&As[(wr * 64 + m * 16 + c) * 64 + off]);
#pragma unroll
            for (int nn = 0; nn < 4; ++nn)
                bb[nn] = *(const bfx8*)(&Bs[(wc * 64 + nn * 16 + c) * 64 + off]);
#pragma unroll
            for (int m = 0; m < 4; ++m)
#pragma unroll
                for (int nn = 0; nn < 4; ++nn)
                    acc[m][nn] = mfma16(af[m], bb[nn], acc[m][nn]);
        }
    };

    issue(0, sm, sm + 8192);
    writeA(0, sm);
    __syncthreads();
    for (int s = 0; s < nsteps; ++s) {
        bf16* Ac = sm + (s & 1) * 16384;
        bf16* An = sm + (((s & 1) ^ 1) * 16384);
        const bool more = (s + 1 < nsteps);
        if (more) issue(s + 1, An, An + 8192);
        compute(Ac, Ac + 8192);
        if (more) writeA(s + 1, An);
        __syncthreads();
    }

    if (mode == 3) {
        float* C = g.Cf;
#pragma unroll
        for (int m = 0; m < 4; ++m)
#pragma unroll
            for (int nn = 0; nn < 4; ++nn)
#pragma unroll
                for (int i = 0; i < 4; ++i) {
                    int row = mbase + wr * 64 + m * 16 + quad * 4 + i;
                    int col = nbase + wc * 64 + nn * 16 + c;
                    C[(long)row * 512 + col] = acc[m][nn][i];
                }
        return;
    }

    if (mode == 1) {
        bf16* CT = g.Cb + ((long)(mbase >> 9)) * 262144;
        const int s0 = mbase & 511;
        for (int h = 0; h < 2; ++h) {
            if (wr == h) {
#pragma unroll
                for (int m = 0; m < 4; ++m)
#pragma unroll
                    for (int nn = 0; nn < 4; ++nn)
#pragma unroll
                        for (int i = 0; i < 4; ++i)
                            sm[(wc * 64 + nn * 16 + c) * 64 + m * 16 + quad * 4 + i] =
                                (bf16)acc[m][nn][i];
            }
            __syncthreads();
            {
                const bf16* src = sm + (t >> 1) * 64 + (t & 1) * 32;
                bf16* d = CT + (long)(nbase + (t >> 1)) * 512 + s0 + h * 64 + (t & 1) * 32;
#pragma unroll
                for (int j = 0; j < 4; ++j) *(bfx8*)(d + j * 8) = *(const bfx8*)(src + j * 8);
            }
            __syncthreads();
        }
        return;
    }

    for (int h = 0; h < 2; ++h) {
        if (wr == h) {
#pragma unroll
            for (int m = 0; m < 4; ++m)
#pragma unroll
                for (int nn = 0; nn < 4; ++nn)
#pragma unroll
                    for (int i = 0; i < 4; ++i) {
                        int col = wc * 64 + nn * 16 + c;
                        float v = acc[m][nn][i];
                        if (mode == 2) v = fmaxf(v + g.bias[nbase + col], 0.f);
                        else v *= g.cscale;
                        bf16 hv = (bf16)v;
                        sm[(m * 16 + quad * 4 + i) * 128 + col] = hv;
                        if (mode == 2)
                            sm[8192 + (m * 16 + quad * 4 + i) * 128 + col] =
                                (bf16)(v - (float)hv);
                    }
        }
        __syncthreads();
        {
            const int row = t >> 2, seg = t & 3;
            const bf16* src = sm + row * 128 + seg * 32;
            bf16* d = g.Cb + (long)(mbase + h * 64 + row) * 512 + nbase + seg * 32;
#pragma unroll
            for (int j = 0; j < 4; ++j) *(bfx8*)(d + j * 8) = *(const bfx8*)(src + j * 8);
            if (mode == 2) {
                const bf16* src2 = sm + 8192 + row * 128 + seg * 32;
                bf16* d2 = g.Cl + (long)(mbase + h * 64 + row) * 512 + nbase + seg * 32;
#pragma unroll
                for (int j = 0; j < 4; ++j) *(bfx8*)(d2 + j * 8) = *(const bfx8*)(src2 + j * 8);
            }
        }
        __syncthreads();
    }
}

// ---------------------------------------------------------------------------
// Fused GRU (R12): LDS-staged weights, split Xg + split hp, fast tanh.
// ---------------------------------------------------------------------------
__global__ __launch_bounds__(256) void gru_fused_kernel(
    const bf16* __restrict__ Xh, const bf16* __restrict__ Xl,
    const float* __restrict__ hp,
    const bf16* __restrict__ wih, const bf16* __restrict__ wil,
    const bf16* __restrict__ whh, const bf16* __restrict__ whl,
    const float* __restrict__ gbi, const float* __restrict__ gbh,
    const float* __restrict__ pa, const float* __restrict__ Wsigma,
    const float* __restrict__ Wrho,
    const float* __restrict__ lenv, const float* __restrict__ stepv,
    float* __restrict__ muv, float* __restrict__ sigv) {
    __shared__ bf16 Wh[192][72], Wl[192][72];
    __shared__ float biL[384];

    const int b = blockIdx.x;
    const int qb = b & 7, nh = b >> 3, hd = nh & 7, n = nh >> 3;
    const int t = threadIdx.x;
    const int w = t >> 6, lane = t & 63, quad = lane >> 4, c = lane & 15;
    const int q0 = qb * 64 + w * 16;

    if (t < 192) { biL[t] = gbi[t]; biL[192 + t] = gbh[t]; }
#pragma unroll
    for (int it = 0; it < 6; ++it) {
        int task = it * 256 + t;
        int r = task >> 3, ch = task & 7;
        *(bfx8*)(&Wh[r][ch * 8]) = *(const bfx8*)(wih + r * 64 + ch * 8);
        *(bfx8*)(&Wl[r][ch * 8]) = *(const bfx8*)(wil + r * 64 + ch * 8);
    }
    __syncthreads();

    const v4f zero4 = {0.f, 0.f, 0.f, 0.f};
    v4f gi[12], gh[12];
#pragma unroll
    for (int nt = 0; nt < 12; ++nt) gi[nt] = zero4;
#pragma unroll
    for (int ks = 0; ks < 2; ++ks) {
        long ao = (long)(n * 512 + q0 + c) * 512 + hd * 64 + ks * 32 + quad * 8;
        bfx8 xh = *(const bfx8*)(Xh + ao);
        bfx8 xl = *(const bfx8*)(Xl + ao);
#pragma unroll
        for (int nt = 0; nt < 12; ++nt) {
            bfx8 bh = *(const bfx8*)(&Wh[nt * 16 + c][ks * 32 + quad * 8]);
            bfx8 bl = *(const bfx8*)(&Wl[nt * 16 + c][ks * 32 + quad * 8]);
            gi[nt] = mfma16(xh, bh, gi[nt]);
            gi[nt] = mfma16(xh, bl, gi[nt]);
            gi[nt] = mfma16(xl, bh, gi[nt]);
        }
    }
    __syncthreads();
#pragma unroll
    for (int it = 0; it < 6; ++it) {
        int task = it * 256 + t;
        int r = task >> 3, ch = task & 7;
        *(bfx8*)(&Wh[r][ch * 8]) = *(const bfx8*)(whh + r * 64 + ch * 8);
        *(bfx8*)(&Wl[r][ch * 8]) = *(const bfx8*)(whl + r * 64 + ch * 8);
    }
    __syncthreads();
#pragma unroll
    for (int nt = 0; nt < 12; ++nt) gh[nt] = zero4;
#pragma unroll
    for (int ks = 0; ks < 2; ++ks) {
        bfx8 ah, al;
        split8(hp + (long)(nh * 512 + q0 + c) * 64 + ks * 32 + quad * 8, ah, al);
#pragma unroll
        for (int nt = 0; nt < 12; ++nt) {
            bfx8 bh = *(const bfx8*)(&Wh[nt * 16 + c][ks * 32 + quad * 8]);
            bfx8 bl = *(const bfx8*)(&Wl[nt * 16 + c][ks * 32 + quad * 8]);
            gh[nt] = mfma16(ah, bh, gh[nt]);
            gh[nt] = mfma16(ah, bl, gh[nt]);
            gh[nt] = mfma16(al, bh, gh[nt]);
        }
    }

    float st[4][4];
#pragma unroll
    for (int t4 = 0; t4 < 4; ++t4) {
        float bir = biL[t4 * 16 + c];
        float biz = biL[64 + t4 * 16 + c];
        float bin = biL[128 + t4 * 16 + c];
        float bhr = biL[192 + t4 * 16 + c];
        float bhz = biL[256 + t4 * 16 + c];
        float bhn = biL[320 + t4 * 16 + c];
#pragma unroll
        for (int i = 0; i < 4; ++i) {
            int row = q0 + quad * 4 + i;
            float r = sigm(gi[t4][i] + bir + gh[t4][i] + bhr);
            float z = sigm(gi[t4 + 4][i] + biz + gh[t4 + 4][i] + bhz);
            float nn_ = tanh_fast(gi[t4 + 8][i] + bin + r * (gh[t4 + 8][i] + bhn));
            float hpv = hp[(long)(nh * 512 + row) * 64 + t4 * 16 + c];
            st[t4][i] = (1.0f - z) * nn_ + z * hpv;
        }
    }

    float ws_[4], wr0[4], wr1[4], wr2[4];
#pragma unroll
    for (int t4 = 0; t4 < 4; ++t4) {
        int d = t4 * 16 + c;
        ws_[t4] = Wsigma[hd * 64 + d];
        wr0[t4] = Wrho[(hd * 64 + d) * 3 + 0];
        wr1[t4] = Wrho[(hd * 64 + d) * 3 + 1];
        wr2[t4] = Wrho[(hd * 64 + d) * 3 + 2];
    }
#pragma unroll
    for (int i = 0; i < 4; ++i) {
        float s0 = 0.f, s1 = 0.f, s2 = 0.f, s3 = 0.f;
#pragma unroll
        for (int t4 = 0; t4 < 4; ++t4) {
            float sv = st[t4][i];
            s0 += sv * ws_[t4];
            s1 += sv * wr0[t4];
            s2 += sv * wr1[t4];
            s3 += sv * wr2[t4];
        }
#pragma unroll
        for (int o = 1; o < 16; o <<= 1) {
            s0 += __shfl_xor(s0, o);
            s1 += __shfl_xor(s1, o);
            s2 += __shfl_xor(s2, o);
            s3 += __shfl_xor(s3, o);
        }
        if (c == 0) {
            int row = q0 + quad * 4 + i;
            int idx = nh * 512 + row, rq = n * 512 + row;
            float L = lenv[rq], sp = stepv[rq];
            float sg = (fmaxf(s0, 0.f) + 0.27f) / L;
            float fl = floorf(s1);
            float steps = fl + sigm(10.0f * (fabsf(s1 - fl) - 0.5f));
            float ag = sigm(s2), bg = sigm(s3);
            float mu_ = steps * sp + ag * pa[idx] + bg;
            float mu = fmaxf(0.01f * mu_, fminf(mu_, 1.0f + 0.01f * mu_));
            muv[idx] = mu;
            sigv[idx] = sg;
        }
    }
}

// ---------------------------------------------------------------------------
// Fused attention: single barrier; MFMA row-sums; exp2-direct.
// Pp/Pg [16][512] with XOR swizzle k^((row&7)<<3) -> LDS exactly 32 KB,
// 5 blocks/CU (__launch_bounds__(256,5)). att stored PRE-SWIZZLED (BK=64).
// ---------------------------------------------------------------------------
__global__ __launch_bounds__(256, 5) void attn_fused_kernel(
    const bf16* __restrict__ Qh, const bf16* __restrict__ Kh,
    const bf16* __restrict__ VhT, const unsigned* __restrict__ mpack,
    const float* __restrict__ vpos, const float* __restrict__ mixv,
    const float* __restrict__ stepv, const float* __restrict__ muv,
    const float* __restrict__ sigv, bf16* __restrict__ att) {
    __shared__ bf16 Pp[16][512];
    __shared__ bf16 Pg[16][512];

    const int b = blockIdx.x;
    const int nh = ((b >> 8) << 3) | (b & 7);
    const int qt = (b >> 3) & 31;
    const int hd = nh & 7, n = nh >> 3;
    const int t = threadIdx.x;
    const int wave = t >> 6, lane = t & 63;
    const int quad = lane >> 4, c = lane & 15;
    const int qloc = quad * 4;

    const bf16* qrow = Qh + (long)(n * 512 + qt * 16 + c) * 512 + hd * 64 + quad * 8;
    bfx8 afr0 = *(const bfx8*)qrow;
    bfx8 afr1 = *(const bfx8*)(qrow + 32);

    const v4f zero4 = {0.f, 0.f, 0.f, 0.f};
    v4f acc[8];
#pragma unroll
    for (int i = 0; i < 8; ++i) acc[i] = zero4;

    const bf16* kbase = Kh + (long)(n * 512 + wave * 128 + c) * 512 + hd * 64 + quad * 8;
#pragma unroll
    for (int t8 = 0; t8 < 8; ++t8) {
        bfx8 b0 = *(const bfx8*)(kbase + (long)t8 * 16 * 512);
        bfx8 b1 = *(const bfx8*)(kbase + (long)t8 * 16 * 512 + 32);
        acc[t8] = mfma16(afr0, b0, acc[t8]);
        acc[t8] = mfma16(afr1, b1, acc[t8]);
    }

    float mu_[4], c2n[4], stp[4];
#pragma unroll
    for (int i = 0; i < 4; ++i) {
        int q = qt * 16 + qloc + i;
        int idx = nh * 512 + q, rq = n * 512 + q;
        mu_[i] = muv[idx];
        float sg = sigv[idx];
        c2n[i] = -0.72134752f / (sg * sg);   // -0.5*log2(e)/sigma^2
        stp[i] = stepv[rq];
    }

    const unsigned mb32 = mpack[(long)(n * 32 + qt) * 256 + t];
    unsigned mbits[4];
#pragma unroll
    for (int i = 0; i < 4; ++i) mbits[i] = (mb32 >> (8 * i)) & 0xffu;

    float vp[8];
#pragma unroll
    for (int t8 = 0; t8 < 8; ++t8) vp[t8] = vpos[wave * 128 + t8 * 16 + c];

#pragma unroll
    for (int i = 0; i < 4; ++i) {
        float m = mu_[i], s = stp[i], cg = c2n[i];
        const int rsw = ((qloc + i) & 7) << 3;
#pragma unroll
        for (int t8 = 0; t8 < 8; ++t8) {
            int on = (mbits[i] >> t8) & 1;
            float pv = on ? __builtin_amdgcn_exp2f(acc[t8][i]) : 0.f;
            float d = vp[t8] * s - m;
            float gv = on ? __builtin_amdgcn_exp2f(d * d * cg) : 0.f;
            int k = (wave * 128 + t8 * 16 + c) ^ rsw;
            Pp[qloc + i][k] = (bf16)pv;
            Pg[qloc + i][k] = (bf16)gv;
        }
    }

    __syncthreads();  // the ONLY barrier

    bfx8 ones;
#pragma unroll
    for (int j = 0; j < 8; ++j) ones[j] = (bf16)1.0f;

    v4f accP = zero4, accG = zero4, accS = zero4, accT = zero4;
    const bf16* vrow = VhT + (long)(n * 512 + hd * 64 + wave * 16 + c) * 512 + quad * 8;
    const int csw = (c & 7) << 3;
    __builtin_amdgcn_s_setprio(1);
#pragma unroll
    for (int ks = 0; ks < 16; ++ks) {
        bfx8 bf_ = *(const bfx8*)(vrow + ks * 32);
        const int kr = (ks * 32 + quad * 8) ^ csw;
        bfx8 ap = *(const bfx8*)(&Pp[c][kr]);
        bfx8 ag = *(const bfx8*)(&Pg[c][kr]);
        accP = mfma16(ap, bf_, accP);
        accG = mfma16(ag, bf_, accG);
        accS = mfma16(ap, ones, accS);
        accT = mfma16(ag, ones, accT);
    }
    __builtin_amdgcn_s_setprio(0);

#pragma unroll
    for (int i = 0; i < 4; ++i) {
        float Sp = accS[i];
        float Sg = accT[i] + 512.0f * 1e-20f;
        float m_ = mixv[n * 512 + qt * 16 + qloc + i];
        float aci = (1.0f - m_) / Sp;
        float bci = m_ / Sg;
        int q = qt * 16 + quad * 4 + i;
        int cx = (wave * 16 + c) ^ (((quad * 4 + i) & 7) << 3);  // BK=64 pre-swizzle
        att[(long)(n * 512 + q) * 512 + hd * 64 + cx] =
            (bf16)(aci * accP[i] + bci * accG[i]);
    }
}

// ---------------------------------------------------------------------------
extern "C" void kernel_launch(void* const* d_in, const int* in_sizes, int n_in,
                              void* d_out, int out_size, void* d_ws, size_t ws_size,
                              hipStream_t stream) {
    (void)in_sizes; (void)n_in; (void)out_size; (void)ws_size;

    const float* Q = (const float*)d_in[0];
    const float* K = (const float*)d_in[1];
    const float* V = (const float*)d_in[2];
    const float* past_state = (const float*)d_in[3];
    const float* past_att = (const float*)d_in[4];
    const float* vpos = (const float*)d_in[5];
    const int* mask = (const int*)d_in[6];
    const float* Wq = (const float*)d_in[7];
    const float* Wk = (const float*)d_in[8];
    const float* Wv = (const float*)d_in[9];
    const float* Wpos = (const float*)d_in[10];
    const float* bpos = (const float*)d_in[11];
    const float* Wsigma = (const float*)d_in[12];
    const float* Wrho = (const float*)d_in[13];
    const float* mix_w = (const float*)d_in[14];
    const float* mix_b = (const float*)d_in[15];
    const float* gwi = (const float*)d_in[16];
    const float* gwh = (const float*)d_in[17];
    const float* gbi = (const float*)d_in[18];
    const float* gbh = (const float*)d_in[19];
    const float* Wc = (const float*)d_in[20];
    float* out = (float*)d_out;

    // ---- workspace ----
    char* p = (char*)d_ws;
    const size_t SZB = 8192UL * 512 * 2;
    const size_t SZW = 512UL * 512 * 2;
    bf16* WqT = (bf16*)p;   p += SZW;
    bf16* WkT = (bf16*)p;   p += SZW;
    bf16* WvT = (bf16*)p;   p += SZW;
    bf16* WpT = (bf16*)p;   p += SZW;
    bf16* WpTl = (bf16*)p;  p += SZW;
    bf16* WcT = (bf16*)p;   p += SZW;
    bf16* wih = (bf16*)p;   p += 24576;
    bf16* wil = (bf16*)p;   p += 24576;
    bf16* whh = (bf16*)p;   p += 24576;
    bf16* whl = (bf16*)p;   p += 24576;
    bf16* Qh = (bf16*)p;    p += SZB;
    bf16* Kh = (bf16*)p;    p += SZB;
    bf16* VhT = (bf16*)p;   p += SZB;
    bf16* Xh = (bf16*)p;
    bf16* att = Xh;         p += SZB;
    bf16* Xl = (bf16*)p;    p += SZB;
    unsigned* mpack = (unsigned*)p;      p += 16UL * 32 * 256 * 4;
    float* mixv = (float*)p;  p += 32768;
    float* stepv = (float*)p; p += 32768;
    float* lenv = (float*)p;  p += 32768;
    float* muv = (float*)p;   p += 262144;
    float* sigv = (float*)p;  p += 262144;

    dim3 blk(256);

    PrepArgs pa;
    pa.wsrc[0] = Wq; pa.wsrc[1] = Wk; pa.wsrc[2] = Wv; pa.wsrc[3] = Wpos; pa.wsrc[4] = Wc;
    pa.wdst[0] = WqT; pa.wdst[1] = WkT; pa.wdst[2] = WvT; pa.wdst[3] = WpT; pa.wdst[4] = WcT;
    pa.wdstlo[0] = nullptr; pa.wdstlo[1] = nullptr; pa.wdstlo[2] = nullptr;
    pa.wdstlo[3] = WpTl; pa.wdstlo[4] = nullptr;
    pa.gwi = gwi; pa.gwh = gwh;
    pa.wih = wih; pa.wil = wil; pa.whh = whh; pa.whl = whl;
    pa.Q = Q; pa.mask = mask; pa.mix_w = mix_w; pa.mix_b = mix_b;
    pa.mixv = mixv; pa.stepv = stepv; pa.lenv = lenv; pa.mpack = mpack;
    prep_kernel<<<dim3(834), blk, 0, stream>>>(pa);

    // projections: d[0]=split (longest, z=0 first), d[1]=Q (cscale for exp2),
    // d[2]=K, d[3]=V(T)
    G4 gp;
    gp.d[0].Af = Q;  gp.d[0].Ab = nullptr; gp.d[0].B0 = WpT; gp.d[0].B1 = WpTl;
    gp.d[0].bias = bpos; gp.d[0].Cb = Xh; gp.d[0].Cl = Xl; gp.d[0].Cf = nullptr;
    gp.d[0].mode = 2; gp.d[0].cscale = 1.0f;
    gp.d[1].Af = Q;  gp.d[1].Ab = nullptr; gp.d[1].B0 = WqT; gp.d[1].B1 = nullptr;
    gp.d[1].bias = nullptr; gp.d[1].Cb = Qh; gp.d[1].Cl = nullptr; gp.d[1].Cf = nullptr;
    gp.d[1].mode = 0; gp.d[1].cscale = 0.125f * 1.44269504089f;
    gp.d[2].Af = K;  gp.d[2].Ab = nullptr; gp.d[2].B0 = WkT; gp.d[2].B1 = nullptr;
    gp.d[2].bias = nullptr; gp.d[2].Cb = Kh; gp.d[2].Cl = nullptr; gp.d[2].Cf = nullptr;
    gp.d[2].mode = 0; gp.d[2].cscale = 1.0f;
    gp.d[3].Af = V;  gp.d[3].Ab = nullptr; gp.d[3].B0 = WvT; gp.d[3].B1 = nullptr;
    gp.d[3].bias = nullptr; gp.d[3].Cb = VhT; gp.d[3].Cl = nullptr; gp.d[3].Cf = nullptr;
    gp.d[3].mode = 1; gp.d[3].cscale = 1.0f;
    gemm128<<<dim3(64, 4, 4), blk, 0, stream>>>(gp);

    gru_fused_kernel<<<dim3(1024), blk, 0, stream>>>(
        Xh, Xl, past_state, wih, wil, whh, whl, gbi, gbh, past_att, Wsigma, Wrho,
        lenv, stepv, muv, sigv);

    attn_fused_kernel<<<dim3(4096), blk, 0, stream>>>(
        Qh, Kh, VhT, mpack, vpos, mixv, stepv, muv, sigv, att);

    G4 go;
    go.d[0].Af = nullptr; go.d[0].Ab = att; go.d[0].B0 = WcT; go.d[0].B1 = nullptr;
    go.d[0].bias = nullptr; go.d[0].Cb = nullptr; go.d[0].Cl = nullptr; go.d[0].Cf = out;
    go.d[0].mode = 3; go.d[0].cscale = 1.0f;
    go.d[1] = go.d[0]; go.d[2] = go.d[0]; go.d[3] = go.d[0];  // unused
    gemm128<<<dim3(64, 4, 1), blk, 0, stream>>>(go);
}